// Round 16
// baseline (351.982 us; speedup 1.0000x reference)
//
#include <hip/hip_runtime.h>
#include <math.h>

#define BB   4
#define NN   8192
#define BN   (BB*NN)       // 32768 points per cloud-set; 8 clouds of 8192 total
#define KNN  10
#define G    32            // grid cells per dim
#define NCELLS (G*G*G)     // 32768 cells per cloud
#define GRID_LO (-5.0f)
#define H    0.3125f       // 10/32
#define INV_H 3.2f
#define RCAP 2             // rho<=2 region; beyond -> brute overflow

#define SEPS    5.9604645e-8f        // slamch('E') = 2^-24
#define SEPS2   (SEPS*SEPS)
#define SSAFMIN 1.1754944e-38f

__device__ __forceinline__ int cellc(float v) {
    int c = (int)floorf((v - GRID_LO) * INV_H);
    return min(G - 1, max(0, c));
}

// ---------------------------------------------------------------------------
// Kernel A: build P4[8][8192] = (x,y,z, bitcast orig-idx); clouds 0-3 = gt
// batches, 4-7 = pred[idx12] batches. Histogram cells + zero accumulators.
// ---------------------------------------------------------------------------
__global__ __launch_bounds__(256) void prep_kernel(
    const float* __restrict__ gt, const float* __restrict__ pred,
    const unsigned* __restrict__ idxw, float4* __restrict__ P4,
    int* __restrict__ hist, float* __restrict__ accum,
    unsigned* __restrict__ counter, int* __restrict__ ovf_count)
{
    __shared__ int s_is32;
    int tid = threadIdx.x;
    if (tid == 0) s_is32 = 0;
    __syncthreads();
    if (idxw[2*tid + 1] != 0u) s_is32 = 1;   // int64 => all high words 0
    __syncthreads();
    bool is64 = (s_is32 == 0);

    if (blockIdx.x == 0 && tid == 0) {
        *accum = 0.0f; *counter = 0u; *ovf_count = 0;
    }

    int point = blockIdx.x * 256 + tid;        // 0 .. 2*BN-1
    int pair = point >> 13;                    // 0..7
    int r    = point & (NN - 1);               // idx within cloud
    float x, y, z;
    if (point < BN) {
        const float* s = gt + (size_t)point*3;
        x = s[0]; y = s[1]; z = s[2];
    } else {
        int rr = point - BN;
        int b = rr >> 13;
        unsigned idx = is64 ? idxw[2*(size_t)rr] : idxw[rr];
        const float* s = pred + ((size_t)b*NN + idx)*3;
        x = s[0]; y = s[1]; z = s[2];
    }
    P4[point] = make_float4(x, y, z, __int_as_float(r));
    int cell = (cellc(z)*G + cellc(y))*G + cellc(x);
    atomicAdd(&hist[(size_t)pair*NCELLS + cell], 1);
}

// ---------------------------------------------------------------------------
// Kernel B: per-cloud exclusive scan -> combo[c] = int2(start, count).
// ---------------------------------------------------------------------------
__global__ __launch_bounds__(1024) void scan_kernel(
    const int* __restrict__ hist, int2* __restrict__ combo)
{
    int cloud = blockIdx.x;
    int tid = threadIdx.x;
    int lane = tid & 63, wid = tid >> 6;
    const int* h = hist + (size_t)cloud * NCELLS;
    int2* cb = combo + (size_t)cloud * NCELLS;

    int loc[32];
    int base = tid * 32;
    const int4* h4 = (const int4*)(h + base);
    int sum = 0;
    #pragma unroll
    for (int i = 0; i < 8; ++i) {
        int4 a = h4[i];
        loc[4*i+0] = a.x; loc[4*i+1] = a.y; loc[4*i+2] = a.z; loc[4*i+3] = a.w;
        sum += a.x + a.y + a.z + a.w;
    }
    // inclusive wave scan of sums
    int v = sum;
    #pragma unroll
    for (int off = 1; off < 64; off <<= 1) {
        int o = __shfl_up(v, off, 64);
        if (lane >= off) v += o;
    }
    __shared__ int ws[16], wsx[16];
    if (lane == 63) ws[wid] = v;
    __syncthreads();
    if (tid < 16) {
        int acc = 0;
        for (int i = 0; i < tid; ++i) acc += ws[i];
        wsx[tid] = acc;
    }
    __syncthreads();
    int run = (v - sum) + wsx[wid];            // exclusive prefix for this thread

    int4* cb4 = (int4*)(cb + base);            // 2 cells per int4 store
    #pragma unroll
    for (int i = 0; i < 16; ++i) {
        int4 o;
        o.x = run; o.y = loc[2*i];     run += loc[2*i];
        o.z = run; o.w = loc[2*i+1];   run += loc[2*i+1];
        cb4[i] = o;
    }
}

// ---------------------------------------------------------------------------
// Kernel C: scatter points into cell-sorted S.
// ---------------------------------------------------------------------------
__global__ __launch_bounds__(256) void scatter_kernel(
    const float4* __restrict__ P4, int* __restrict__ hist,
    const int2* __restrict__ combo, float4* __restrict__ S)
{
    int point = blockIdx.x * 256 + threadIdx.x;
    float4 p = P4[point];
    int pair = point >> 13;
    int cell = (cellc(p.z)*G + cellc(p.y))*G + cellc(p.x);
    int old = atomicSub(&hist[(size_t)pair*NCELLS + cell], 1);
    int pos = combo[(size_t)pair*NCELLS + cell].x + old - 1;
    S[(size_t)pair*NN + pos] = p;
}

// ---------------------------------------------------------------------------
// LAPACK ssyevd 3x3 path: ssytrd('L') + sorgtr + ssteqr('V'). Sign-faithful.
// (verified absmax 0.0 in rounds 2-15 — do not touch)
// ---------------------------------------------------------------------------
__device__ __forceinline__ float f_sign(float a, float b) {
    return copysignf(a, b);
}
__device__ __forceinline__ float slapy2(float x, float y) {
#pragma clang fp contract(off)
    float xa = fabsf(x), ya = fabsf(y);
    float w = fmaxf(xa, ya), z = fminf(xa, ya);
    if (z == 0.0f) return w;
    float t = z / w;
    return w * __fsqrt_rn(1.0f + t*t);
}
__device__ __forceinline__ void slartg_(float f, float g, float* cs, float* sn, float* r) {
#pragma clang fp contract(off)
    if (g == 0.0f)      { *cs = 1.0f; *sn = 0.0f; *r = f; }
    else if (f == 0.0f) { *cs = 0.0f; *sn = f_sign(1.0f, g); *r = fabsf(g); }
    else {
        float f1 = fabsf(f);
        float d = __fsqrt_rn(f*f + g*g);
        float p = 1.0f / d;
        *cs = f1 * p;
        *sn = g * f_sign(p, f);
        *r  = f_sign(d, f);
    }
}
__device__ void slaev2_(float a, float b, float c,
                        float* rt1, float* rt2, float* cs1, float* sn1) {
#pragma clang fp contract(off)
    float sm = a + c, df = a - c;
    float adf = fabsf(df);
    float tb = b + b;
    float ab = fabsf(tb);
    float acmx, acmn;
    if (fabsf(a) > fabsf(c)) { acmx = a; acmn = c; } else { acmx = c; acmn = a; }
    float rt;
    if (adf > ab)      { float t = ab/adf; rt = adf*__fsqrt_rn(1.0f + t*t); }
    else if (adf < ab) { float t = adf/ab; rt = ab*__fsqrt_rn(1.0f + t*t); }
    else               { rt = ab*__fsqrt_rn(2.0f); }
    int sgn1;
    if (sm < 0.0f)      { *rt1 = 0.5f*(sm - rt); sgn1 = -1;
                          *rt2 = (acmx / *rt1)*acmn - (b / *rt1)*b; }
    else if (sm > 0.0f) { *rt1 = 0.5f*(sm + rt); sgn1 = 1;
                          *rt2 = (acmx / *rt1)*acmn - (b / *rt1)*b; }
    else                { *rt1 = 0.5f*rt; *rt2 = -0.5f*rt; sgn1 = 1; }
    float cs; int sgn2;
    if (df >= 0.0f) { cs = df + rt; sgn2 = 1; } else { cs = df - rt; sgn2 = -1; }
    float acs = fabsf(cs);
    float c1, s1;
    if (acs > ab) { float ct = -tb/cs; s1 = 1.0f/__fsqrt_rn(1.0f + ct*ct); c1 = ct*s1; }
    else {
        if (ab == 0.0f) { c1 = 1.0f; s1 = 0.0f; }
        else { float tn = -cs/tb; c1 = 1.0f/__fsqrt_rn(1.0f + tn*tn); s1 = tn*c1; }
    }
    if (sgn1 == sgn2) { float tn = c1; c1 = -s1; s1 = tn; }
    *cs1 = c1; *sn1 = s1;
}

__device__ void eigh3_smallest(float c00, float c01, float c02,
                               float c11, float c12, float c22, float nv[3])
{
#pragma clang fp contract(off)
    // ---- ssytrd('L') ----
    float d[4], e[3], z[4][4];
    float tau1, v2 = 0.0f;
    float e1, d2, d3, e2;
    float alpha = c01, x = c02;
    if (x == 0.0f) {
        tau1 = 0.0f; e1 = alpha;
        d2 = c11; d3 = c22; e2 = c12;
    } else {
        float beta = -f_sign(slapy2(alpha, fabsf(x)), alpha);
        tau1 = (beta - alpha) / beta;
        v2 = x / (alpha - beta);
        e1 = beta;
        float w1 = tau1*(c11 + c12*v2);
        float w2 = tau1*(c12 + c22*v2);
        float al = -0.5f*tau1*(w1 + w2*v2);
        w1 = w1 + al;
        w2 = w2 + al*v2;
        d2 = (c11 - w1) - w1;
        e2 = (c12 - v2*w1) - w2;
        d3 = (c22 - v2*w2) - w2*v2;
    }
    d[1] = c00; d[2] = d2; d[3] = d3;
    e[1] = e1;  e[2] = e2;
    z[1][1] = 1.0f; z[1][2] = 0.0f; z[1][3] = 0.0f;
    z[2][1] = 0.0f; z[3][1] = 0.0f;
    z[2][2] = 1.0f - tau1;
    float mtv = -tau1*v2;
    z[2][3] = mtv; z[3][2] = mtv;
    z[3][3] = 1.0f + mtv*v2;

    // ---- ssteqr('V', 3) ----
    const int n = 3, nm1 = 2;
    int l1 = 1, jtot = 0;
    const int nmaxit = 90;
    float cw[3], sw[3];
    int guard = 0;
    while (guard++ < 64) {
        if (l1 > n) break;
        if (l1 > 1) e[l1-1] = 0.0f;
        int m = n;
        if (l1 <= nm1) {
            for (int mi = l1; mi <= nm1; ++mi) {
                float tst = fabsf(e[mi]);
                if (tst == 0.0f) { m = mi; break; }
                if (tst <= (__fsqrt_rn(fabsf(d[mi]))*__fsqrt_rn(fabsf(d[mi+1])))*SEPS) {
                    e[mi] = 0.0f; m = mi; break;
                }
            }
        }
        int l = l1;
        int lsv = l, lend = m, lendsv = lend;
        l1 = m + 1;
        if (lend == l) continue;
        if (fabsf(d[lend]) < fabsf(d[l])) { lend = lsv; l = lendsv; }

        if (lend > l) {
            // QL
            while (true) {
                int m_ = lend;
                if (l != lend) {
                    for (int mi = l; mi <= lend-1; ++mi) {
                        float em = e[mi];
                        float tst = em*em;
                        if (tst <= (SEPS2*fabsf(d[mi]))*fabsf(d[mi+1]) + SSAFMIN) { m_ = mi; break; }
                    }
                }
                if (m_ < lend) e[m_] = 0.0f;
                float p = d[l];
                if (m_ == l) {
                    d[l] = p; l = l + 1;
                    if (l <= lend) continue; else break;
                }
                if (m_ == l + 1) {
                    float rt1, rt2, cc, ss;
                    slaev2_(d[l], e[l], d[l+1], &rt1, &rt2, &cc, &ss);
                    for (int i = 1; i <= 3; ++i) {
                        float tmp = z[i][l+1];
                        z[i][l+1] = cc*tmp - ss*z[i][l];
                        z[i][l]   = ss*tmp + cc*z[i][l];
                    }
                    d[l] = rt1; d[l+1] = rt2; e[l] = 0.0f;
                    l = l + 2;
                    if (l <= lend) continue; else break;
                }
                if (jtot == nmaxit) break;
                jtot++;
                float g = (d[l+1] - p) / (2.0f*e[l]);
                float r = slapy2(g, 1.0f);
                g = d[m_] - p + (e[l] / (g + f_sign(r, g)));
                float s = 1.0f, c = 1.0f;
                p = 0.0f;
                for (int i = m_-1; i >= l; --i) {
                    float f = s*e[i];
                    float b = c*e[i];
                    slartg_(g, f, &c, &s, &r);
                    if (i != m_-1) e[i+1] = r;
                    g = d[i+1] - p;
                    r = (d[i] - g)*s + (2.0f*c)*b;
                    p = s*r;
                    d[i+1] = g + p;
                    g = c*r - b;
                    cw[i] = c; sw[i] = -s;
                }
                for (int j = m_-1; j >= l; --j) {
                    float cc = cw[j], ss = sw[j];
                    for (int i = 1; i <= 3; ++i) {
                        float tmp = z[i][j+1];
                        z[i][j+1] = cc*tmp - ss*z[i][j];
                        z[i][j]   = ss*tmp + cc*z[i][j];
                    }
                }
                d[l] = d[l] - p;
                e[l] = g;
            }
        } else {
            // QR
            while (true) {
                int m_ = lend;
                if (l != lend) {
                    for (int mi = l; mi >= lend+1; --mi) {
                        float em = e[mi-1];
                        float tst = em*em;
                        if (tst <= (SEPS2*fabsf(d[mi]))*fabsf(d[mi-1]) + SSAFMIN) { m_ = mi; break; }
                    }
                }
                if (m_ > lend) e[m_-1] = 0.0f;
                float p = d[l];
                if (m_ == l) {
                    d[l] = p; l = l - 1;
                    if (l >= lend) continue; else break;
                }
                if (m_ == l - 1) {
                    float rt1, rt2, cc, ss;
                    slaev2_(d[l-1], e[l-1], d[l], &rt1, &rt2, &cc, &ss);
                    for (int i = 1; i <= 3; ++i) {
                        float tmp = z[i][l];
                        z[i][l]   = cc*tmp - ss*z[i][l-1];
                        z[i][l-1] = ss*tmp + cc*z[i][l-1];
                    }
                    d[l-1] = rt1; d[l] = rt2; e[l-1] = 0.0f;
                    l = l - 2;
                    if (l >= lend) continue; else break;
                }
                if (jtot == nmaxit) break;
                jtot++;
                float g = (d[l-1] - p) / (2.0f*e[l-1]);
                float r = slapy2(g, 1.0f);
                g = d[m_] - p + (e[l-1] / (g + f_sign(r, g)));
                float s = 1.0f, c = 1.0f;
                p = 0.0f;
                for (int i = m_; i <= l-1; ++i) {
                    float f = s*e[i];
                    float b = c*e[i];
                    slartg_(g, f, &c, &s, &r);
                    if (i != m_) e[i-1] = r;
                    g = d[i] - p;
                    r = (d[i+1] - g)*s + (2.0f*c)*b;
                    p = s*r;
                    d[i] = g + p;
                    g = c*r - b;
                    cw[i] = c; sw[i] = s;
                }
                for (int j = m_; j <= l-1; ++j) {
                    float cc = cw[j], ss = sw[j];
                    for (int i = 1; i <= 3; ++i) {
                        float tmp = z[i][j+1];
                        z[i][j+1] = cc*tmp - ss*z[i][j];
                        z[i][j]   = ss*tmp + cc*z[i][j];
                    }
                }
                d[l] = d[l] - p;
                e[l-1] = g;
            }
        }
    }
    for (int ii = 2; ii <= 3; ++ii) {
        int i = ii - 1, k = i;
        float p = d[i];
        for (int j = ii; j <= 3; ++j) if (d[j] < p) { k = j; p = d[j]; }
        if (k != i) {
            d[k] = d[i]; d[i] = p;
            for (int r2 = 1; r2 <= 3; ++r2) {
                float t = z[r2][i]; z[r2][i] = z[r2][k]; z[r2][k] = t;
            }
        }
    }
    nv[0] = z[1][1]; nv[1] = z[2][1]; nv[2] = z[3][1];
}

// Shared epilogue math: covariance of the sorted 10-neighborhood + eigh.
__device__ void normal_compute(const float4* __restrict__ cl,
                               const unsigned long long keys[KNN],
                               float nv[3])
{
#pragma clang fp contract(off)
    float px[KNN], py[KNN], pz[KNN];
    float sx = 0.f, sy = 0.f, sz = 0.f;
    #pragma unroll
    for (int s = 0; s < KNN; ++s) {
        int ni = (int)(unsigned)(keys[s] & 0xFFFFFFFFull);
        float4 np = cl[ni];
        px[s] = np.x; py[s] = np.y; pz[s] = np.z;
        sx = sx + px[s]; sy = sy + py[s]; sz = sz + pz[s];
    }
    float mx = sx / 10.0f, my = sy / 10.0f, mz = sz / 10.0f;
    float c00=0.f,c01=0.f,c02=0.f,c11=0.f,c12=0.f,c22=0.f;
    #pragma unroll
    for (int s = 0; s < KNN; ++s) {
        float dx = px[s]-mx, dy = py[s]-my, dz = pz[s]-mz;
        c00 = c00 + dx*dx; c01 = c01 + dx*dy; c02 = c02 + dx*dz;
        c11 = c11 + dy*dy; c12 = c12 + dy*dz; c22 = c22 + dz*dz;
    }
    c00 = c00/10.0f; c01 = c01/10.0f; c02 = c02/10.0f;
    c11 = c11/10.0f; c12 = c12/10.0f; c22 = c22/10.0f;
    eigh3_smallest(c00, c01, c02, c11, c12, c22, nv);
}

// candidate insert (strict u64 key compare == top_k (d, idx) tie semantics)
#define PROC(p) do { \
    float ddx = qx - (p).x, ddy = qy - (p).y, ddz = qz - (p).z; \
    float dd = fmaf(ddz, ddz, fmaf(ddy, ddy, ddx*ddx)); \
    unsigned long long key = \
        ((unsigned long long)__float_as_uint(dd) << 32) | \
        (unsigned)__float_as_int((p).w); \
    if (key < k9) { \
        unsigned long long ck = key; \
        _Pragma("unroll") \
        for (int s = 0; s < KNN; ++s) { \
            unsigned long long ok2 = keys[s]; \
            bool sw = ok2 > ck; \
            keys[s] = sw ? ck : ok2; \
            ck      = sw ? ok2 : ck; \
        } \
        k9 = keys[KNN-1]; \
        worst = __uint_as_float((unsigned)(k9 >> 32)); \
    } \
} while (0)

// stream a contiguous candidate segment [b, b+n) of S — 2 loads in flight
#define SEGPROC(b, n) do { \
    int _j = (b), _je = (b) + (n); \
    for (; _j + 2 <= _je; _j += 2) { \
        float4 _p0 = cs[_j]; float4 _p1 = cs[_j+1]; \
        PROC(_p0); PROC(_p1); \
    } \
    if (_j < _je) { float4 _p0 = cs[_j]; PROC(_p0); } \
} while (0)

// ---------------------------------------------------------------------------
// Kernel D (R16): grid 10-NN, TWO lanes per query, walk PARTITIONED (not
// replicated — R5/R7's failure) by compile-time checkerboard: every slot's
// coords are (sub ? constB : constA), so both lanes run the same static code
// on disjoint segments. Per-wave issue ~ half of R12's 43-segment walk;
// waves 1024 -> 2048 (2/SIMD). Exactness: per-lane top-10 of offered subset
// (strict u64 keys); pruning bound = fmin(own worst, bshared) where bshared
// = min of the two lane 10ths after phase 1 — any lane's running 10th >=
// global 10th (subset property), so pruned candidates are provably outside
// the top-10 (ties pass, strict >). Final shfl_xor(width 2) merge -> exact
// sorted global top-10; resolved test on merged 10th == R12 -> identical
// overflow set.
// ---------------------------------------------------------------------------
__global__ __launch_bounds__(256) void knn_main_kernel(
    const float4* __restrict__ P4, const float4* __restrict__ S,
    const int2* __restrict__ combo, float* __restrict__ Nrm,
    int* __restrict__ ovf, unsigned long long* __restrict__ ovf_key,
    int* __restrict__ ovf_count)
{
    int tidg = blockIdx.x * 256 + threadIdx.x;  // 0..131071
    int qid  = tidg >> 1;                       // 0..65535
    int sub  = tidg & 1;
    int pair = qid >> 13;                       // 8 clouds
    int spos = qid & (NN - 1);                  // sorted position
    const float4* __restrict__ cl = P4 + (size_t)pair * NN;
    const float4* __restrict__ cs = S  + (size_t)pair * NN;
    const int2*   __restrict__ cb = combo + (size_t)pair * NCELLS;

    float4 q = cs[spos];
    float qx = q.x, qy = q.y, qz = q.z;
    int qi = __float_as_int(q.w);               // original index in cloud
    int qcx = cellc(qx), qcy = cellc(qy), qcz = cellc(qz);

    unsigned long long keys[KNN];
    #pragma unroll
    for (int s = 0; s < KNN; ++s) keys[s] = 0xFFFFFFFFFFFFFFFFull;
    unsigned long long k9 = keys[KNN-1];
    float worst = __uint_as_float(0xFFFFFFFFu); // NaN: all strict-> tests false

    // ---- phase 1: rho<=1 cube, 9 rows checkerboarded 5/4 over lanes ----
    int x0 = max(qcx - 1, 0), x1 = min(qcx + 1, G - 1);
#define P1SLOT(i, DZA, DYA, DZB, DYB) \
    int rb##i = 0, re##i = 0; \
    { int zz = qcz + (sub ? (DZB) : (DZA)); \
      int yy = qcy + (sub ? (DYB) : (DYA)); \
      if ((unsigned)zz < G && (unsigned)yy < G) { \
          int cbase = (zz*G + yy)*G; \
          int2 a = cb[cbase + x0]; \
          int2 b = cb[cbase + x1]; \
          rb##i = a.x; re##i = b.x + b.y; } }
    P1SLOT(0, -1,-1, -1, 0)
    P1SLOT(1, -1, 1,  0,-1)
    P1SLOT(2,  0, 0,  0, 1)
    P1SLOT(3,  1,-1,  1, 0)
    P1SLOT(4,  1, 1, 99,99)            // lane1 slot4 invalid -> bounds fail
#undef P1SLOT
#define P1GO(i) SEGPROC(rb##i, re##i - rb##i);
    P1GO(0) P1GO(1) P1GO(2) P1GO(3) P1GO(4)
#undef P1GO

    // ---- exchange: shared bound = min of lane 10ths (NaN = missing) ----
    unsigned ow32 = (unsigned)__shfl_xor((int)(unsigned)(k9 >> 32), 1, 2);
    float bshared = fminf(worst, __uint_as_float(ow32));

    // ---- phase 2: rho=2 shell (skip iff H^2 > bshared; conservative) ----
    bool skip = (H*H > bshared);                // NaN-safe: NaN -> walk shell
    {
        int xs0 = max(qcx - 2, 0), xs1 = min(qcx + 2, G - 1);
        // 16 outer rows, checkerboarded 8/8
#define S2SLOT(i, DZA, DYA, DZB, DYB) \
        int sb##i = 0, sn##i = 0; \
        if (!skip) { \
          int zz = qcz + (sub ? (DZB) : (DZA)); \
          int yy = qcy + (sub ? (DYB) : (DYA)); \
          if ((unsigned)zz < G && (unsigned)yy < G) { \
              float loy = fmaf((float)yy, H, GRID_LO); \
              float loz = fmaf((float)zz, H, GRID_LO); \
              float py = fmaxf(0.0f, fmaxf(loy - qy, qy - (loy + H))); \
              float pz = fmaxf(0.0f, fmaxf(loz - qz, qz - (loz + H))); \
              float pyz = fmaf(pz, pz, py*py); \
              float pw = fminf(worst, bshared); \
              if (!(pyz > pw)) { \
                  int cbase = (zz*G + yy)*G; \
                  int2 a = cb[cbase + xs0]; \
                  int2 b = cb[cbase + xs1]; \
                  sb##i = a.x; sn##i = (b.x + b.y) - a.x; } } }
        S2SLOT(0, -2,-2, -2,-1)
        S2SLOT(1, -2, 0, -2, 1)
        S2SLOT(2, -2, 2,  2,-2)
        S2SLOT(3,  2,-1,  2, 0)
        S2SLOT(4,  2, 1,  2, 2)
        S2SLOT(5, -1,-2, -1, 2)
        S2SLOT(6,  0, 2,  0,-2)
        S2SLOT(7,  1,-2,  1, 2)
#undef S2SLOT
        // 18 isolated cells: 9 static (dz,dy) slots, dx = sub ? +2 : -2
#define CSLOT(i, DZ, DY) \
        int tb##i = 0, tn##i = 0; \
        if (!skip) { \
          int zz = qcz + (DZ), yy = qcy + (DY); \
          int xx = qcx + (sub ? 2 : -2); \
          if ((unsigned)zz < G && (unsigned)yy < G && (unsigned)xx < G) { \
              float lox = fmaf((float)xx, H, GRID_LO); \
              float loy = fmaf((float)yy, H, GRID_LO); \
              float loz = fmaf((float)zz, H, GRID_LO); \
              float px = fmaxf(0.0f, fmaxf(lox - qx, qx - (lox + H))); \
              float py = fmaxf(0.0f, fmaxf(loy - qy, qy - (loy + H))); \
              float pz = fmaxf(0.0f, fmaxf(loz - qz, qz - (loz + H))); \
              float m2 = fmaf(pz, pz, fmaf(py, py, px*px)); \
              float pw = fminf(worst, bshared); \
              if (!(m2 > pw)) { \
                  int2 a = cb[(zz*G + yy)*G + xx]; \
                  tb##i = a.x; tn##i = a.y; } } }
        CSLOT(0,-1,-1) CSLOT(1,-1,0) CSLOT(2,-1,1)
        CSLOT(3, 0,-1) CSLOT(4, 0,0) CSLOT(5, 0,1)
        CSLOT(6, 1,-1) CSLOT(7, 1,0) CSLOT(8, 1,1)
#undef CSLOT
#define S2GO(i) SEGPROC(sb##i, sn##i);
        S2GO(0) S2GO(1) S2GO(2) S2GO(3) S2GO(4) S2GO(5) S2GO(6) S2GO(7)
#undef S2GO
#define CGO(i) SEGPROC(tb##i, tn##i);
        CGO(0) CGO(1) CGO(2) CGO(3) CGO(4) CGO(5) CGO(6) CGO(7) CGO(8)
#undef CGO
    }

    // ---- merge the 2 per-lane sorted lists -> exact global top-10 ----
    {
        unsigned long long other[KNN];
        #pragma unroll
        for (int s = 0; s < KNN; ++s)
            other[s] = __shfl_xor(keys[s], 1, 2);   // snapshot before inserts
        #pragma unroll
        for (int s = 0; s < KNN; ++s) {
            unsigned long long key = other[s];
            if (key < k9) {
                unsigned long long ck = key;
                #pragma unroll
                for (int t = 0; t < KNN; ++t) {
                    unsigned long long ok2 = keys[t];
                    bool sw = ok2 > ck;
                    keys[t] = sw ? ck : ok2;
                    ck      = sw ? ok2 : ck;
                }
                k9 = keys[KNN-1];
            }
        }
    }
    float worst_m = __uint_as_float((unsigned)(k9 >> 32));

    // resolved iff cells beyond the rho<=2 region (gap >= 2H) cannot contribute
    float bf = (float)RCAP * H;
    bool resolved = (bf*bf > worst_m);          // strict; NaN (unfilled) -> false
    if (resolved) {
        float nv[3];
        normal_compute(cl, keys, nv);           // both lanes (same data, no div)
        if (sub == 0) {
            float* o = Nrm + ((size_t)pair*NN + qi)*3;
            o[0] = nv[0]; o[1] = nv[1]; o[2] = nv[2];
        }
    } else if (sub == 0) {
        int pos = atomicAdd(ovf_count, 1);
        ovf[pos] = (pair << 13) | qi;
        ovf_key[pos] = k9;      // merged 10th-best: valid upper bound on true
    }                           // 10th key (subset 10th >= full-set 10th)
}

// ---------------------------------------------------------------------------
// Kernel D2: brute-force overflow (R14 config — best measured), one query
// per block (256 thr = 4 waves). The main-phase 10th-best key is a proven
// upper bound on the true 10th key, so candidates with dd > bound_d skip the
// insert chain entirely. bound_d = NaN for unfilled lists -> gate passes
// everything (NaN-safe). Scan 4 loads in flight (stride 1024, 8 iters).
// ---------------------------------------------------------------------------
#define BRUTE_BLOCKS 4096
__global__ __launch_bounds__(256) void brute_kernel(
    const float4* __restrict__ P4, const int* __restrict__ ovf,
    const unsigned long long* __restrict__ ovf_key,
    const int* __restrict__ ovf_count, float* __restrict__ Nrm)
{
    __shared__ unsigned long long wl[4][KNN];
    int tid = threadIdx.x;
    int lane = tid & 63;
    int wid = tid >> 6;
    int count = *ovf_count;

    for (int oi = blockIdx.x; oi < count; oi += BRUTE_BLOCKS) {
        int rec = ovf[oi];
        unsigned long long bound = ovf_key[oi];
        float bound_d = __uint_as_float((unsigned)(bound >> 32)); // NaN if unfilled
        int pair = rec >> 13;
        int qi = rec & (NN - 1);
        const float4* __restrict__ cl = P4 + (size_t)pair * NN;
        float4 q = cl[qi];
        float qx = q.x, qy = q.y, qz = q.z;

        unsigned long long keys[KNN];
        #pragma unroll
        for (int s = 0; s < KNN; ++s) keys[s] = 0xFFFFFFFFFFFFFFFFull;
        unsigned long long k9 = keys[KNN-1];

        // per-lane scan with bound gate; ties at dd==bound_d pass (exact)
#define BPROC(p, jj) do { \
        float ddx = qx - (p).x, ddy = qy - (p).y, ddz = qz - (p).z; \
        float dd = fmaf(ddz, ddz, fmaf(ddy, ddy, ddx*ddx)); \
        if (!(dd > bound_d)) { \
            unsigned long long key = \
                ((unsigned long long)__float_as_uint(dd) << 32) | (unsigned)(jj); \
            if (key < k9) { \
                unsigned long long ck = key; \
                _Pragma("unroll") \
                for (int s = 0; s < KNN; ++s) { \
                    unsigned long long ok2 = keys[s]; \
                    bool sw = ok2 > ck; \
                    keys[s] = sw ? ck : ok2; \
                    ck      = sw ? ok2 : ck; \
                } \
                k9 = keys[KNN-1]; \
            } \
        } \
    } while (0)
        #pragma unroll 1
        for (int j = tid; j < NN; j += 1024) {  // 8 iterations, 4 loads each
            float4 p0 = cl[j];
            float4 p1 = cl[j + 256];
            float4 p2 = cl[j + 512];
            float4 p3 = cl[j + 768];
            BPROC(p0, j);
            BPROC(p1, j + 256);
            BPROC(p2, j + 512);
            BPROC(p3, j + 768);
        }
#undef BPROC

        // in-wave tree merge -> every lane holds its wave's top-10
        #pragma unroll
        for (int m = 1; m < 64; m <<= 1) {
            unsigned long long other[KNN];
            #pragma unroll
            for (int s = 0; s < KNN; ++s)
                other[s] = __shfl_xor(keys[s], m);  // snapshot before inserts
            #pragma unroll
            for (int s = 0; s < KNN; ++s) {
                unsigned long long key = other[s];
                if (key < k9) {
                    unsigned long long ck = key;
                    #pragma unroll
                    for (int t = 0; t < KNN; ++t) {
                        unsigned long long ok2 = keys[t];
                        bool sw = ok2 > ck;
                        keys[t] = sw ? ck : ok2;
                        ck      = sw ? ok2 : ck;
                    }
                    k9 = keys[KNN-1];
                }
            }
        }

        // cross-wave merge via LDS (4 sorted lists)
        if (lane == 0) {
            #pragma unroll
            for (int s = 0; s < KNN; ++s) wl[wid][s] = keys[s];
        }
        __syncthreads();
        if (wid == 0) {
            for (int w2 = 1; w2 < 4; ++w2) {
                #pragma unroll
                for (int s = 0; s < KNN; ++s) {
                    unsigned long long key = wl[w2][s];
                    if (key >= k9) break;       // lists sorted ascending
                    unsigned long long ck = key;
                    #pragma unroll
                    for (int t = 0; t < KNN; ++t) {
                        unsigned long long ok2 = keys[t];
                        bool sw = ok2 > ck;
                        keys[t] = sw ? ck : ok2;
                        ck      = sw ? ok2 : ck;
                    }
                    k9 = keys[KNN-1];
                }
            }
            if (lane == 0) {
                float nv[3];
                normal_compute(cl, keys, nv);
                float* o = Nrm + ((size_t)pair*NN + qi)*3;
                o[0] = nv[0]; o[1] = nv[1]; o[2] = nv[2];
            }
        }
        __syncthreads();                        // protect wl for next query
    }
}

// ---------------------------------------------------------------------------
// Kernel E: per-point 1 - cos, block partial sums, device-scope atomic
// accumulate; last block writes the mean.
// ---------------------------------------------------------------------------
__global__ __launch_bounds__(256) void loss_final_kernel(
    const float* __restrict__ Nrm, float* __restrict__ accum,
    unsigned* __restrict__ counter, float* __restrict__ out)
{
    int tid = threadIdx.x;
    int i = blockIdx.x * 256 + tid;            // 0..BN-1
    const float* g = Nrm + (size_t)i*3;
    const float* p = Nrm + ((size_t)BN + i)*3;
    float gx=g[0], gy=g[1], gz=g[2];
    float hx=p[0], hy=p[1], hz=p[2];
    float dot = fmaf(gx,hx,fmaf(gy,hy,gz*hz));
    float ng  = sqrtf(fmaf(gx,gx,fmaf(gy,gy,gz*gz)));
    float nh  = sqrtf(fmaf(hx,hx,fmaf(hy,hy,hz*hz)));
    float den = fmaxf(ng*nh, 1e-8f);
    float v = 1.0f - dot/den;

    __shared__ float red[256];
    red[tid] = v;
    __syncthreads();
    for (int s = 128; s > 0; s >>= 1) {
        if (tid < s) red[tid] += red[tid+s];
        __syncthreads();
    }
    if (tid == 0) {
        atomicAdd(accum, red[0]);
        __threadfence();
        unsigned old = atomicAdd(counter, 1u);
        if (old == (unsigned)(BN/256 - 1)) {
            float tot = atomicAdd(accum, 0.0f);
            out[0] = tot * (1.0f/(float)BN);
        }
    }
}

// ---------------------------------------------------------------------------
extern "C" void kernel_launch(void* const* d_in, const int* in_sizes, int n_in,
                              void* d_out, int out_size, void* d_ws, size_t ws_size,
                              hipStream_t stream)
{
    (void)in_sizes; (void)n_in; (void)out_size; (void)ws_size;
    const float*    gt   = (const float*)d_in[0];
    const float*    pred = (const float*)d_in[1];
    const unsigned* idxw = (const unsigned*)d_in[2];
    float* out = (float*)d_out;

    char* w = (char*)d_ws;
    float4* P4   = (float4*)w;                         w += (size_t)2*BN*16;   // 1 MB
    float4* S    = (float4*)w;                         w += (size_t)2*BN*16;   // 1 MB
    int*    hist = (int*)w;                            w += (size_t)8*NCELLS*4;   // 1 MB
    int2*   combo = (int2*)w;                          w += (size_t)8*NCELLS*8;   // 2 MB
    float*  Nrm  = (float*)w;                          w += (size_t)2*BN*3*4;  // 0.75 MB
    float*  accum = (float*)w;                         w += 16;
    unsigned* counter = (unsigned*)(accum + 1);
    int*    ovf_count = (int*)(accum + 2);
    int*    ovf  = (int*)w;                            w += (size_t)2*BN*4;    // 0.25 MB
    unsigned long long* ovf_key = (unsigned long long*)w;  w += (size_t)2*BN*8; // 0.5 MB

    hipMemsetAsync(hist, 0, (size_t)8*NCELLS*4, stream);
    hipLaunchKernelGGL(prep_kernel,    dim3(2*BN/256), dim3(256),  0, stream,
                       gt, pred, idxw, P4, hist, accum, counter, ovf_count);
    hipLaunchKernelGGL(scan_kernel,    dim3(8),        dim3(1024), 0, stream,
                       hist, combo);
    hipLaunchKernelGGL(scatter_kernel, dim3(2*BN/256), dim3(256),  0, stream,
                       P4, hist, combo, S);
    hipLaunchKernelGGL(knn_main_kernel, dim3(2*BN*2/256), dim3(256), 0, stream,
                       P4, S, combo, Nrm, ovf, ovf_key, ovf_count);
    hipLaunchKernelGGL(brute_kernel,   dim3(BRUTE_BLOCKS), dim3(256), 0, stream,
                       P4, ovf, ovf_key, ovf_count, Nrm);
    hipLaunchKernelGGL(loss_final_kernel, dim3(BN/256), dim3(256), 0, stream,
                       Nrm, accum, counter, out);
}

// Round 17
// 327.151 us; speedup vs baseline: 1.0759x; 1.0759x over previous
//
#include <hip/hip_runtime.h>
#include <math.h>

#define BB   4
#define NN   8192
#define BN   (BB*NN)       // 32768 points per cloud-set; 8 clouds of 8192 total
#define KNN  10
#define G    32            // grid cells per dim
#define NCELLS (G*G*G)     // 32768 cells per cloud
#define GRID_LO (-5.0f)
#define H    0.3125f       // 10/32
#define INV_H 3.2f
#define RCAP 2             // rho<=2 region; beyond -> brute overflow

#define SEPS    5.9604645e-8f        // slamch('E') = 2^-24
#define SEPS2   (SEPS*SEPS)
#define SSAFMIN 1.1754944e-38f

__device__ __forceinline__ int cellc(float v) {
    int c = (int)floorf((v - GRID_LO) * INV_H);
    return min(G - 1, max(0, c));
}

// ---------------------------------------------------------------------------
// Kernel A: build P4[8][8192] = (x,y,z, bitcast orig-idx); clouds 0-3 = gt
// batches, 4-7 = pred[idx12] batches. Histogram cells + zero accumulators.
// ---------------------------------------------------------------------------
__global__ __launch_bounds__(256) void prep_kernel(
    const float* __restrict__ gt, const float* __restrict__ pred,
    const unsigned* __restrict__ idxw, float4* __restrict__ P4,
    int* __restrict__ hist, float* __restrict__ accum,
    unsigned* __restrict__ counter, int* __restrict__ ovf_count)
{
    __shared__ int s_is32;
    int tid = threadIdx.x;
    if (tid == 0) s_is32 = 0;
    __syncthreads();
    if (idxw[2*tid + 1] != 0u) s_is32 = 1;   // int64 => all high words 0
    __syncthreads();
    bool is64 = (s_is32 == 0);

    if (blockIdx.x == 0 && tid == 0) {
        *accum = 0.0f; *counter = 0u; *ovf_count = 0;
    }

    int point = blockIdx.x * 256 + tid;        // 0 .. 2*BN-1
    int pair = point >> 13;                    // 0..7
    int r    = point & (NN - 1);               // idx within cloud
    float x, y, z;
    if (point < BN) {
        const float* s = gt + (size_t)point*3;
        x = s[0]; y = s[1]; z = s[2];
    } else {
        int rr = point - BN;
        int b = rr >> 13;
        unsigned idx = is64 ? idxw[2*(size_t)rr] : idxw[rr];
        const float* s = pred + ((size_t)b*NN + idx)*3;
        x = s[0]; y = s[1]; z = s[2];
    }
    P4[point] = make_float4(x, y, z, __int_as_float(r));
    int cell = (cellc(z)*G + cellc(y))*G + cellc(x);
    atomicAdd(&hist[(size_t)pair*NCELLS + cell], 1);
}

// ---------------------------------------------------------------------------
// Kernel B: per-cloud exclusive scan -> combo[c] = int2(start, count).
// ---------------------------------------------------------------------------
__global__ __launch_bounds__(1024) void scan_kernel(
    const int* __restrict__ hist, int2* __restrict__ combo)
{
    int cloud = blockIdx.x;
    int tid = threadIdx.x;
    int lane = tid & 63, wid = tid >> 6;
    const int* h = hist + (size_t)cloud * NCELLS;
    int2* cb = combo + (size_t)cloud * NCELLS;

    int loc[32];
    int base = tid * 32;
    const int4* h4 = (const int4*)(h + base);
    int sum = 0;
    #pragma unroll
    for (int i = 0; i < 8; ++i) {
        int4 a = h4[i];
        loc[4*i+0] = a.x; loc[4*i+1] = a.y; loc[4*i+2] = a.z; loc[4*i+3] = a.w;
        sum += a.x + a.y + a.z + a.w;
    }
    // inclusive wave scan of sums
    int v = sum;
    #pragma unroll
    for (int off = 1; off < 64; off <<= 1) {
        int o = __shfl_up(v, off, 64);
        if (lane >= off) v += o;
    }
    __shared__ int ws[16], wsx[16];
    if (lane == 63) ws[wid] = v;
    __syncthreads();
    if (tid < 16) {
        int acc = 0;
        for (int i = 0; i < tid; ++i) acc += ws[i];
        wsx[tid] = acc;
    }
    __syncthreads();
    int run = (v - sum) + wsx[wid];            // exclusive prefix for this thread

    int4* cb4 = (int4*)(cb + base);            // 2 cells per int4 store
    #pragma unroll
    for (int i = 0; i < 16; ++i) {
        int4 o;
        o.x = run; o.y = loc[2*i];     run += loc[2*i];
        o.z = run; o.w = loc[2*i+1];   run += loc[2*i+1];
        cb4[i] = o;
    }
}

// ---------------------------------------------------------------------------
// Kernel C: scatter points into cell-sorted S.
// ---------------------------------------------------------------------------
__global__ __launch_bounds__(256) void scatter_kernel(
    const float4* __restrict__ P4, int* __restrict__ hist,
    const int2* __restrict__ combo, float4* __restrict__ S)
{
    int point = blockIdx.x * 256 + threadIdx.x;
    float4 p = P4[point];
    int pair = point >> 13;
    int cell = (cellc(p.z)*G + cellc(p.y))*G + cellc(p.x);
    int old = atomicSub(&hist[(size_t)pair*NCELLS + cell], 1);
    int pos = combo[(size_t)pair*NCELLS + cell].x + old - 1;
    S[(size_t)pair*NN + pos] = p;
}

// ---------------------------------------------------------------------------
// LAPACK ssyevd 3x3 path: ssytrd('L') + sorgtr + ssteqr('V'). Sign-faithful.
// (verified absmax 0.0 in rounds 2-16 — do not touch)
// ---------------------------------------------------------------------------
__device__ __forceinline__ float f_sign(float a, float b) {
    return copysignf(a, b);
}
__device__ __forceinline__ float slapy2(float x, float y) {
#pragma clang fp contract(off)
    float xa = fabsf(x), ya = fabsf(y);
    float w = fmaxf(xa, ya), z = fminf(xa, ya);
    if (z == 0.0f) return w;
    float t = z / w;
    return w * __fsqrt_rn(1.0f + t*t);
}
__device__ __forceinline__ void slartg_(float f, float g, float* cs, float* sn, float* r) {
#pragma clang fp contract(off)
    if (g == 0.0f)      { *cs = 1.0f; *sn = 0.0f; *r = f; }
    else if (f == 0.0f) { *cs = 0.0f; *sn = f_sign(1.0f, g); *r = fabsf(g); }
    else {
        float f1 = fabsf(f);
        float d = __fsqrt_rn(f*f + g*g);
        float p = 1.0f / d;
        *cs = f1 * p;
        *sn = g * f_sign(p, f);
        *r  = f_sign(d, f);
    }
}
__device__ void slaev2_(float a, float b, float c,
                        float* rt1, float* rt2, float* cs1, float* sn1) {
#pragma clang fp contract(off)
    float sm = a + c, df = a - c;
    float adf = fabsf(df);
    float tb = b + b;
    float ab = fabsf(tb);
    float acmx, acmn;
    if (fabsf(a) > fabsf(c)) { acmx = a; acmn = c; } else { acmx = c; acmn = a; }
    float rt;
    if (adf > ab)      { float t = ab/adf; rt = adf*__fsqrt_rn(1.0f + t*t); }
    else if (adf < ab) { float t = adf/ab; rt = ab*__fsqrt_rn(1.0f + t*t); }
    else               { rt = ab*__fsqrt_rn(2.0f); }
    int sgn1;
    if (sm < 0.0f)      { *rt1 = 0.5f*(sm - rt); sgn1 = -1;
                          *rt2 = (acmx / *rt1)*acmn - (b / *rt1)*b; }
    else if (sm > 0.0f) { *rt1 = 0.5f*(sm + rt); sgn1 = 1;
                          *rt2 = (acmx / *rt1)*acmn - (b / *rt1)*b; }
    else                { *rt1 = 0.5f*rt; *rt2 = -0.5f*rt; sgn1 = 1; }
    float cs; int sgn2;
    if (df >= 0.0f) { cs = df + rt; sgn2 = 1; } else { cs = df - rt; sgn2 = -1; }
    float acs = fabsf(cs);
    float c1, s1;
    if (acs > ab) { float ct = -tb/cs; s1 = 1.0f/__fsqrt_rn(1.0f + ct*ct); c1 = ct*s1; }
    else {
        if (ab == 0.0f) { c1 = 1.0f; s1 = 0.0f; }
        else { float tn = -cs/tb; c1 = 1.0f/__fsqrt_rn(1.0f + tn*tn); s1 = tn*c1; }
    }
    if (sgn1 == sgn2) { float tn = c1; c1 = -s1; s1 = tn; }
    *cs1 = c1; *sn1 = s1;
}

__device__ void eigh3_smallest(float c00, float c01, float c02,
                               float c11, float c12, float c22, float nv[3])
{
#pragma clang fp contract(off)
    // ---- ssytrd('L') ----
    float d[4], e[3], z[4][4];
    float tau1, v2 = 0.0f;
    float e1, d2, d3, e2;
    float alpha = c01, x = c02;
    if (x == 0.0f) {
        tau1 = 0.0f; e1 = alpha;
        d2 = c11; d3 = c22; e2 = c12;
    } else {
        float beta = -f_sign(slapy2(alpha, fabsf(x)), alpha);
        tau1 = (beta - alpha) / beta;
        v2 = x / (alpha - beta);
        e1 = beta;
        float w1 = tau1*(c11 + c12*v2);
        float w2 = tau1*(c12 + c22*v2);
        float al = -0.5f*tau1*(w1 + w2*v2);
        w1 = w1 + al;
        w2 = w2 + al*v2;
        d2 = (c11 - w1) - w1;
        e2 = (c12 - v2*w1) - w2;
        d3 = (c22 - v2*w2) - w2*v2;
    }
    d[1] = c00; d[2] = d2; d[3] = d3;
    e[1] = e1;  e[2] = e2;
    z[1][1] = 1.0f; z[1][2] = 0.0f; z[1][3] = 0.0f;
    z[2][1] = 0.0f; z[3][1] = 0.0f;
    z[2][2] = 1.0f - tau1;
    float mtv = -tau1*v2;
    z[2][3] = mtv; z[3][2] = mtv;
    z[3][3] = 1.0f + mtv*v2;

    // ---- ssteqr('V', 3) ----
    const int n = 3, nm1 = 2;
    int l1 = 1, jtot = 0;
    const int nmaxit = 90;
    float cw[3], sw[3];
    int guard = 0;
    while (guard++ < 64) {
        if (l1 > n) break;
        if (l1 > 1) e[l1-1] = 0.0f;
        int m = n;
        if (l1 <= nm1) {
            for (int mi = l1; mi <= nm1; ++mi) {
                float tst = fabsf(e[mi]);
                if (tst == 0.0f) { m = mi; break; }
                if (tst <= (__fsqrt_rn(fabsf(d[mi]))*__fsqrt_rn(fabsf(d[mi+1])))*SEPS) {
                    e[mi] = 0.0f; m = mi; break;
                }
            }
        }
        int l = l1;
        int lsv = l, lend = m, lendsv = lend;
        l1 = m + 1;
        if (lend == l) continue;
        if (fabsf(d[lend]) < fabsf(d[l])) { lend = lsv; l = lendsv; }

        if (lend > l) {
            // QL
            while (true) {
                int m_ = lend;
                if (l != lend) {
                    for (int mi = l; mi <= lend-1; ++mi) {
                        float em = e[mi];
                        float tst = em*em;
                        if (tst <= (SEPS2*fabsf(d[mi]))*fabsf(d[mi+1]) + SSAFMIN) { m_ = mi; break; }
                    }
                }
                if (m_ < lend) e[m_] = 0.0f;
                float p = d[l];
                if (m_ == l) {
                    d[l] = p; l = l + 1;
                    if (l <= lend) continue; else break;
                }
                if (m_ == l + 1) {
                    float rt1, rt2, cc, ss;
                    slaev2_(d[l], e[l], d[l+1], &rt1, &rt2, &cc, &ss);
                    for (int i = 1; i <= 3; ++i) {
                        float tmp = z[i][l+1];
                        z[i][l+1] = cc*tmp - ss*z[i][l];
                        z[i][l]   = ss*tmp + cc*z[i][l];
                    }
                    d[l] = rt1; d[l+1] = rt2; e[l] = 0.0f;
                    l = l + 2;
                    if (l <= lend) continue; else break;
                }
                if (jtot == nmaxit) break;
                jtot++;
                float g = (d[l+1] - p) / (2.0f*e[l]);
                float r = slapy2(g, 1.0f);
                g = d[m_] - p + (e[l] / (g + f_sign(r, g)));
                float s = 1.0f, c = 1.0f;
                p = 0.0f;
                for (int i = m_-1; i >= l; --i) {
                    float f = s*e[i];
                    float b = c*e[i];
                    slartg_(g, f, &c, &s, &r);
                    if (i != m_-1) e[i+1] = r;
                    g = d[i+1] - p;
                    r = (d[i] - g)*s + (2.0f*c)*b;
                    p = s*r;
                    d[i+1] = g + p;
                    g = c*r - b;
                    cw[i] = c; sw[i] = -s;
                }
                for (int j = m_-1; j >= l; --j) {
                    float cc = cw[j], ss = sw[j];
                    for (int i = 1; i <= 3; ++i) {
                        float tmp = z[i][j+1];
                        z[i][j+1] = cc*tmp - ss*z[i][j];
                        z[i][j]   = ss*tmp + cc*z[i][j];
                    }
                }
                d[l] = d[l] - p;
                e[l] = g;
            }
        } else {
            // QR
            while (true) {
                int m_ = lend;
                if (l != lend) {
                    for (int mi = l; mi >= lend+1; --mi) {
                        float em = e[mi-1];
                        float tst = em*em;
                        if (tst <= (SEPS2*fabsf(d[mi]))*fabsf(d[mi-1]) + SSAFMIN) { m_ = mi; break; }
                    }
                }
                if (m_ > lend) e[m_-1] = 0.0f;
                float p = d[l];
                if (m_ == l) {
                    d[l] = p; l = l - 1;
                    if (l >= lend) continue; else break;
                }
                if (m_ == l - 1) {
                    float rt1, rt2, cc, ss;
                    slaev2_(d[l-1], e[l-1], d[l], &rt1, &rt2, &cc, &ss);
                    for (int i = 1; i <= 3; ++i) {
                        float tmp = z[i][l];
                        z[i][l]   = cc*tmp - ss*z[i][l-1];
                        z[i][l-1] = ss*tmp + cc*z[i][l-1];
                    }
                    d[l-1] = rt1; d[l] = rt2; e[l-1] = 0.0f;
                    l = l - 2;
                    if (l >= lend) continue; else break;
                }
                if (jtot == nmaxit) break;
                jtot++;
                float g = (d[l-1] - p) / (2.0f*e[l-1]);
                float r = slapy2(g, 1.0f);
                g = d[m_] - p + (e[l-1] / (g + f_sign(r, g)));
                float s = 1.0f, c = 1.0f;
                p = 0.0f;
                for (int i = m_; i <= l-1; ++i) {
                    float f = s*e[i];
                    float b = c*e[i];
                    slartg_(g, f, &c, &s, &r);
                    if (i != m_) e[i-1] = r;
                    g = d[i] - p;
                    r = (d[i+1] - g)*s + (2.0f*c)*b;
                    p = s*r;
                    d[i] = g + p;
                    g = c*r - b;
                    cw[i] = c; sw[i] = s;
                }
                for (int j = m_; j <= l-1; ++j) {
                    float cc = cw[j], ss = sw[j];
                    for (int i = 1; i <= 3; ++i) {
                        float tmp = z[i][j+1];
                        z[i][j+1] = cc*tmp - ss*z[i][j];
                        z[i][j]   = ss*tmp + cc*z[i][j];
                    }
                }
                d[l] = d[l] - p;
                e[l-1] = g;
            }
        }
    }
    for (int ii = 2; ii <= 3; ++ii) {
        int i = ii - 1, k = i;
        float p = d[i];
        for (int j = ii; j <= 3; ++j) if (d[j] < p) { k = j; p = d[j]; }
        if (k != i) {
            d[k] = d[i]; d[i] = p;
            for (int r2 = 1; r2 <= 3; ++r2) {
                float t = z[r2][i]; z[r2][i] = z[r2][k]; z[r2][k] = t;
            }
        }
    }
    nv[0] = z[1][1]; nv[1] = z[2][1]; nv[2] = z[3][1];
}

// Covariance of the sorted 10-neighborhood (same op order as rounds 2-16;
// the eigh moved to the fused eigh_loss kernel — pure relocation).
__device__ void cov_compute(const float4* __restrict__ cl,
                            const unsigned long long keys[KNN], float c[6])
{
#pragma clang fp contract(off)
    float px[KNN], py[KNN], pz[KNN];
    float sx = 0.f, sy = 0.f, sz = 0.f;
    #pragma unroll
    for (int s = 0; s < KNN; ++s) {
        int ni = (int)(unsigned)(keys[s] & 0xFFFFFFFFull);
        float4 np = cl[ni];
        px[s] = np.x; py[s] = np.y; pz[s] = np.z;
        sx = sx + px[s]; sy = sy + py[s]; sz = sz + pz[s];
    }
    float mx = sx / 10.0f, my = sy / 10.0f, mz = sz / 10.0f;
    float c00=0.f,c01=0.f,c02=0.f,c11=0.f,c12=0.f,c22=0.f;
    #pragma unroll
    for (int s = 0; s < KNN; ++s) {
        float dx = px[s]-mx, dy = py[s]-my, dz = pz[s]-mz;
        c00 = c00 + dx*dx; c01 = c01 + dx*dy; c02 = c02 + dx*dz;
        c11 = c11 + dy*dy; c12 = c12 + dy*dz; c22 = c22 + dz*dz;
    }
    c[0] = c00/10.0f; c[1] = c01/10.0f; c[2] = c02/10.0f;
    c[3] = c11/10.0f; c[4] = c12/10.0f; c[5] = c22/10.0f;
}

// candidate insert (strict u64 key compare == top_k (d, idx) tie semantics)
#define PROC(p) do { \
    float ddx = qx - (p).x, ddy = qy - (p).y, ddz = qz - (p).z; \
    float dd = fmaf(ddz, ddz, fmaf(ddy, ddy, ddx*ddx)); \
    unsigned long long key = \
        ((unsigned long long)__float_as_uint(dd) << 32) | \
        (unsigned)__float_as_int((p).w); \
    if (key < k9) { \
        unsigned long long ck = key; \
        _Pragma("unroll") \
        for (int s = 0; s < KNN; ++s) { \
            unsigned long long ok2 = keys[s]; \
            bool sw = ok2 > ck; \
            keys[s] = sw ? ck : ok2; \
            ck      = sw ? ok2 : ck; \
        } \
        k9 = keys[KNN-1]; \
        worst = __uint_as_float((unsigned)(k9 >> 32)); \
    } \
} while (0)

// stream a contiguous candidate segment [b, b+n) of S — 2 loads in flight
#define SEGPROC(b, n) do { \
    int _j = (b), _je = (b) + (n); \
    for (; _j + 2 <= _je; _j += 2) { \
        float4 _p0 = cs[_j]; float4 _p1 = cs[_j+1]; \
        PROC(_p0); PROC(_p1); \
    } \
    if (_j < _je) { float4 _p0 = cs[_j]; PROC(_p0); } \
} while (0)

// ---------------------------------------------------------------------------
// Kernel D (R16 structure, R17: eigh removed): grid 10-NN, TWO lanes per
// query, walk partitioned by compile-time checkerboard. Resolved -> store
// covariance (2 float4); unresolved -> overflow + bound key.
// ---------------------------------------------------------------------------
__global__ __launch_bounds__(256) void knn_main_kernel(
    const float4* __restrict__ P4, const float4* __restrict__ S,
    const int2* __restrict__ combo, float4* __restrict__ Cov,
    int* __restrict__ ovf, unsigned long long* __restrict__ ovf_key,
    int* __restrict__ ovf_count)
{
    int tidg = blockIdx.x * 256 + threadIdx.x;  // 0..131071
    int qid  = tidg >> 1;                       // 0..65535
    int sub  = tidg & 1;
    int pair = qid >> 13;                       // 8 clouds
    int spos = qid & (NN - 1);                  // sorted position
    const float4* __restrict__ cl = P4 + (size_t)pair * NN;
    const float4* __restrict__ cs = S  + (size_t)pair * NN;
    const int2*   __restrict__ cb = combo + (size_t)pair * NCELLS;

    float4 q = cs[spos];
    float qx = q.x, qy = q.y, qz = q.z;
    int qi = __float_as_int(q.w);               // original index in cloud
    int qcx = cellc(qx), qcy = cellc(qy), qcz = cellc(qz);

    unsigned long long keys[KNN];
    #pragma unroll
    for (int s = 0; s < KNN; ++s) keys[s] = 0xFFFFFFFFFFFFFFFFull;
    unsigned long long k9 = keys[KNN-1];
    float worst = __uint_as_float(0xFFFFFFFFu); // NaN: all strict-> tests false

    // ---- phase 1: rho<=1 cube, 9 rows checkerboarded 5/4 over lanes ----
    int x0 = max(qcx - 1, 0), x1 = min(qcx + 1, G - 1);
#define P1SLOT(i, DZA, DYA, DZB, DYB) \
    int rb##i = 0, re##i = 0; \
    { int zz = qcz + (sub ? (DZB) : (DZA)); \
      int yy = qcy + (sub ? (DYB) : (DYA)); \
      if ((unsigned)zz < G && (unsigned)yy < G) { \
          int cbase = (zz*G + yy)*G; \
          int2 a = cb[cbase + x0]; \
          int2 b = cb[cbase + x1]; \
          rb##i = a.x; re##i = b.x + b.y; } }
    P1SLOT(0, -1,-1, -1, 0)
    P1SLOT(1, -1, 1,  0,-1)
    P1SLOT(2,  0, 0,  0, 1)
    P1SLOT(3,  1,-1,  1, 0)
    P1SLOT(4,  1, 1, 99,99)            // lane1 slot4 invalid -> bounds fail
#undef P1SLOT
#define P1GO(i) SEGPROC(rb##i, re##i - rb##i);
    P1GO(0) P1GO(1) P1GO(2) P1GO(3) P1GO(4)
#undef P1GO

    // ---- exchange: shared bound = min of lane 10ths (NaN = missing) ----
    unsigned ow32 = (unsigned)__shfl_xor((int)(unsigned)(k9 >> 32), 1, 2);
    float bshared = fminf(worst, __uint_as_float(ow32));

    // ---- phase 2: rho=2 shell (skip iff H^2 > bshared; conservative) ----
    bool skip = (H*H > bshared);                // NaN-safe: NaN -> walk shell
    {
        int xs0 = max(qcx - 2, 0), xs1 = min(qcx + 2, G - 1);
        // 16 outer rows, checkerboarded 8/8
#define S2SLOT(i, DZA, DYA, DZB, DYB) \
        int sb##i = 0, sn##i = 0; \
        if (!skip) { \
          int zz = qcz + (sub ? (DZB) : (DZA)); \
          int yy = qcy + (sub ? (DYB) : (DYA)); \
          if ((unsigned)zz < G && (unsigned)yy < G) { \
              float loy = fmaf((float)yy, H, GRID_LO); \
              float loz = fmaf((float)zz, H, GRID_LO); \
              float py = fmaxf(0.0f, fmaxf(loy - qy, qy - (loy + H))); \
              float pz = fmaxf(0.0f, fmaxf(loz - qz, qz - (loz + H))); \
              float pyz = fmaf(pz, pz, py*py); \
              float pw = fminf(worst, bshared); \
              if (!(pyz > pw)) { \
                  int cbase = (zz*G + yy)*G; \
                  int2 a = cb[cbase + xs0]; \
                  int2 b = cb[cbase + xs1]; \
                  sb##i = a.x; sn##i = (b.x + b.y) - a.x; } } }
        S2SLOT(0, -2,-2, -2,-1)
        S2SLOT(1, -2, 0, -2, 1)
        S2SLOT(2, -2, 2,  2,-2)
        S2SLOT(3,  2,-1,  2, 0)
        S2SLOT(4,  2, 1,  2, 2)
        S2SLOT(5, -1,-2, -1, 2)
        S2SLOT(6,  0, 2,  0,-2)
        S2SLOT(7,  1,-2,  1, 2)
#undef S2SLOT
        // 18 isolated cells: 9 static (dz,dy) slots, dx = sub ? +2 : -2
#define CSLOT(i, DZ, DY) \
        int tb##i = 0, tn##i = 0; \
        if (!skip) { \
          int zz = qcz + (DZ), yy = qcy + (DY); \
          int xx = qcx + (sub ? 2 : -2); \
          if ((unsigned)zz < G && (unsigned)yy < G && (unsigned)xx < G) { \
              float lox = fmaf((float)xx, H, GRID_LO); \
              float loy = fmaf((float)yy, H, GRID_LO); \
              float loz = fmaf((float)zz, H, GRID_LO); \
              float px = fmaxf(0.0f, fmaxf(lox - qx, qx - (lox + H))); \
              float py = fmaxf(0.0f, fmaxf(loy - qy, qy - (loy + H))); \
              float pz = fmaxf(0.0f, fmaxf(loz - qz, qz - (loz + H))); \
              float m2 = fmaf(pz, pz, fmaf(py, py, px*px)); \
              float pw = fminf(worst, bshared); \
              if (!(m2 > pw)) { \
                  int2 a = cb[(zz*G + yy)*G + xx]; \
                  tb##i = a.x; tn##i = a.y; } } }
        CSLOT(0,-1,-1) CSLOT(1,-1,0) CSLOT(2,-1,1)
        CSLOT(3, 0,-1) CSLOT(4, 0,0) CSLOT(5, 0,1)
        CSLOT(6, 1,-1) CSLOT(7, 1,0) CSLOT(8, 1,1)
#undef CSLOT
#define S2GO(i) SEGPROC(sb##i, sn##i);
        S2GO(0) S2GO(1) S2GO(2) S2GO(3) S2GO(4) S2GO(5) S2GO(6) S2GO(7)
#undef S2GO
#define CGO(i) SEGPROC(tb##i, tn##i);
        CGO(0) CGO(1) CGO(2) CGO(3) CGO(4) CGO(5) CGO(6) CGO(7) CGO(8)
#undef CGO
    }

    // ---- merge the 2 per-lane sorted lists -> exact global top-10 ----
    {
        unsigned long long other[KNN];
        #pragma unroll
        for (int s = 0; s < KNN; ++s)
            other[s] = __shfl_xor(keys[s], 1, 2);   // snapshot before inserts
        #pragma unroll
        for (int s = 0; s < KNN; ++s) {
            unsigned long long key = other[s];
            if (key < k9) {
                unsigned long long ck = key;
                #pragma unroll
                for (int t = 0; t < KNN; ++t) {
                    unsigned long long ok2 = keys[t];
                    bool sw = ok2 > ck;
                    keys[t] = sw ? ck : ok2;
                    ck      = sw ? ok2 : ck;
                }
                k9 = keys[KNN-1];
            }
        }
    }
    float worst_m = __uint_as_float((unsigned)(k9 >> 32));

    // resolved iff cells beyond the rho<=2 region (gap >= 2H) cannot contribute
    float bf = (float)RCAP * H;
    bool resolved = (bf*bf > worst_m);          // strict; NaN (unfilled) -> false
    if (resolved) {
        float c[6];
        cov_compute(cl, keys, c);               // both lanes (cheap, no eigh)
        if (sub == 0) {
            size_t o = ((size_t)pair*NN + qi)*2;
            Cov[o]   = make_float4(c[0], c[1], c[2], c[3]);
            Cov[o+1] = make_float4(c[4], c[5], 0.0f, 0.0f);
        }
    } else if (sub == 0) {
        int pos = atomicAdd(ovf_count, 1);
        ovf[pos] = (pair << 13) | qi;
        ovf_key[pos] = k9;      // merged 10th-best: valid upper bound on true
    }                           // 10th key (subset 10th >= full-set 10th)
}

// ---------------------------------------------------------------------------
// Kernel D2: brute-force overflow (R14 config), one query per block. Bound
// gate skips the insert chain for provably-excluded candidates. R17: writes
// covariance instead of running eigh (relocated to eigh_loss).
// ---------------------------------------------------------------------------
#define BRUTE_BLOCKS 4096
__global__ __launch_bounds__(256) void brute_kernel(
    const float4* __restrict__ P4, const int* __restrict__ ovf,
    const unsigned long long* __restrict__ ovf_key,
    const int* __restrict__ ovf_count, float4* __restrict__ Cov)
{
    __shared__ unsigned long long wl[4][KNN];
    int tid = threadIdx.x;
    int lane = tid & 63;
    int wid = tid >> 6;
    int count = *ovf_count;

    for (int oi = blockIdx.x; oi < count; oi += BRUTE_BLOCKS) {
        int rec = ovf[oi];
        unsigned long long bound = ovf_key[oi];
        float bound_d = __uint_as_float((unsigned)(bound >> 32)); // NaN if unfilled
        int pair = rec >> 13;
        int qi = rec & (NN - 1);
        const float4* __restrict__ cl = P4 + (size_t)pair * NN;
        float4 q = cl[qi];
        float qx = q.x, qy = q.y, qz = q.z;

        unsigned long long keys[KNN];
        #pragma unroll
        for (int s = 0; s < KNN; ++s) keys[s] = 0xFFFFFFFFFFFFFFFFull;
        unsigned long long k9 = keys[KNN-1];

        // per-lane scan with bound gate; ties at dd==bound_d pass (exact)
#define BPROC(p, jj) do { \
        float ddx = qx - (p).x, ddy = qy - (p).y, ddz = qz - (p).z; \
        float dd = fmaf(ddz, ddz, fmaf(ddy, ddy, ddx*ddx)); \
        if (!(dd > bound_d)) { \
            unsigned long long key = \
                ((unsigned long long)__float_as_uint(dd) << 32) | (unsigned)(jj); \
            if (key < k9) { \
                unsigned long long ck = key; \
                _Pragma("unroll") \
                for (int s = 0; s < KNN; ++s) { \
                    unsigned long long ok2 = keys[s]; \
                    bool sw = ok2 > ck; \
                    keys[s] = sw ? ck : ok2; \
                    ck      = sw ? ok2 : ck; \
                } \
                k9 = keys[KNN-1]; \
            } \
        } \
    } while (0)
        #pragma unroll 1
        for (int j = tid; j < NN; j += 1024) {  // 8 iterations, 4 loads each
            float4 p0 = cl[j];
            float4 p1 = cl[j + 256];
            float4 p2 = cl[j + 512];
            float4 p3 = cl[j + 768];
            BPROC(p0, j);
            BPROC(p1, j + 256);
            BPROC(p2, j + 512);
            BPROC(p3, j + 768);
        }
#undef BPROC

        // in-wave tree merge -> every lane holds its wave's top-10
        #pragma unroll
        for (int m = 1; m < 64; m <<= 1) {
            unsigned long long other[KNN];
            #pragma unroll
            for (int s = 0; s < KNN; ++s)
                other[s] = __shfl_xor(keys[s], m);  // snapshot before inserts
            #pragma unroll
            for (int s = 0; s < KNN; ++s) {
                unsigned long long key = other[s];
                if (key < k9) {
                    unsigned long long ck = key;
                    #pragma unroll
                    for (int t = 0; t < KNN; ++t) {
                        unsigned long long ok2 = keys[t];
                        bool sw = ok2 > ck;
                        keys[t] = sw ? ck : ok2;
                        ck      = sw ? ok2 : ck;
                    }
                    k9 = keys[KNN-1];
                }
            }
        }

        // cross-wave merge via LDS (4 sorted lists)
        if (lane == 0) {
            #pragma unroll
            for (int s = 0; s < KNN; ++s) wl[wid][s] = keys[s];
        }
        __syncthreads();
        if (wid == 0) {
            for (int w2 = 1; w2 < 4; ++w2) {
                #pragma unroll
                for (int s = 0; s < KNN; ++s) {
                    unsigned long long key = wl[w2][s];
                    if (key >= k9) break;       // lists sorted ascending
                    unsigned long long ck = key;
                    #pragma unroll
                    for (int t = 0; t < KNN; ++t) {
                        unsigned long long ok2 = keys[t];
                        bool sw = ok2 > ck;
                        keys[t] = sw ? ck : ok2;
                        ck      = sw ? ok2 : ck;
                    }
                    k9 = keys[KNN-1];
                }
            }
            if (lane == 0) {
                float c[6];
                cov_compute(cl, keys, c);
                size_t o = ((size_t)pair*NN + qi)*2;
                Cov[o]   = make_float4(c[0], c[1], c[2], c[3]);
                Cov[o+1] = make_float4(c[4], c[5], 0.0f, 0.0f);
            }
        }
        __syncthreads();                        // protect wl for next query
    }
}

// ---------------------------------------------------------------------------
// Kernel E (R17): fused eigh + loss. One thread per point pair: two eighs
// (gt + pred covariances — identical inputs to the old in-kernel eighs ->
// bit-identical normals), then 1 - cos, block reduce, atomic accumulate.
// ---------------------------------------------------------------------------
__global__ __launch_bounds__(256) void eigh_loss_kernel(
    const float4* __restrict__ Cov, float* __restrict__ accum,
    unsigned* __restrict__ counter, float* __restrict__ out)
{
    int tid = threadIdx.x;
    int i = blockIdx.x * 256 + tid;            // 0..BN-1
    float4 a0 = Cov[(size_t)i*2],            a1 = Cov[(size_t)i*2 + 1];
    float4 b0 = Cov[((size_t)BN + i)*2],     b1 = Cov[((size_t)BN + i)*2 + 1];
    float gn[3], pn[3];
    eigh3_smallest(a0.x, a0.y, a0.z, a0.w, a1.x, a1.y, gn);
    eigh3_smallest(b0.x, b0.y, b0.z, b0.w, b1.x, b1.y, pn);

    float gx=gn[0], gy=gn[1], gz=gn[2];
    float hx=pn[0], hy=pn[1], hz=pn[2];
    float dot = fmaf(gx,hx,fmaf(gy,hy,gz*hz));
    float ng  = sqrtf(fmaf(gx,gx,fmaf(gy,gy,gz*gz)));
    float nh  = sqrtf(fmaf(hx,hx,fmaf(hy,hy,hz*hz)));
    float den = fmaxf(ng*nh, 1e-8f);
    float v = 1.0f - dot/den;

    __shared__ float red[256];
    red[tid] = v;
    __syncthreads();
    for (int s = 128; s > 0; s >>= 1) {
        if (tid < s) red[tid] += red[tid+s];
        __syncthreads();
    }
    if (tid == 0) {
        atomicAdd(accum, red[0]);
        __threadfence();
        unsigned old = atomicAdd(counter, 1u);
        if (old == (unsigned)(BN/256 - 1)) {
            float tot = atomicAdd(accum, 0.0f);
            out[0] = tot * (1.0f/(float)BN);
        }
    }
}

// ---------------------------------------------------------------------------
extern "C" void kernel_launch(void* const* d_in, const int* in_sizes, int n_in,
                              void* d_out, int out_size, void* d_ws, size_t ws_size,
                              hipStream_t stream)
{
    (void)in_sizes; (void)n_in; (void)out_size; (void)ws_size;
    const float*    gt   = (const float*)d_in[0];
    const float*    pred = (const float*)d_in[1];
    const unsigned* idxw = (const unsigned*)d_in[2];
    float* out = (float*)d_out;

    char* w = (char*)d_ws;
    float4* P4   = (float4*)w;                         w += (size_t)2*BN*16;   // 1 MB
    float4* S    = (float4*)w;                         w += (size_t)2*BN*16;   // 1 MB
    int*    hist = (int*)w;                            w += (size_t)8*NCELLS*4;   // 1 MB
    int2*   combo = (int2*)w;                          w += (size_t)8*NCELLS*8;   // 2 MB
    float4* Cov  = (float4*)w;                         w += (size_t)2*BN*32;   // 2 MB
    float*  accum = (float*)w;                         w += 16;
    unsigned* counter = (unsigned*)(accum + 1);
    int*    ovf_count = (int*)(accum + 2);
    int*    ovf  = (int*)w;                            w += (size_t)2*BN*4;    // 0.25 MB
    unsigned long long* ovf_key = (unsigned long long*)w;  w += (size_t)2*BN*8; // 0.5 MB

    hipMemsetAsync(hist, 0, (size_t)8*NCELLS*4, stream);
    hipLaunchKernelGGL(prep_kernel,    dim3(2*BN/256), dim3(256),  0, stream,
                       gt, pred, idxw, P4, hist, accum, counter, ovf_count);
    hipLaunchKernelGGL(scan_kernel,    dim3(8),        dim3(1024), 0, stream,
                       hist, combo);
    hipLaunchKernelGGL(scatter_kernel, dim3(2*BN/256), dim3(256),  0, stream,
                       P4, hist, combo, S);
    hipLaunchKernelGGL(knn_main_kernel, dim3(2*BN*2/256), dim3(256), 0, stream,
                       P4, S, combo, Cov, ovf, ovf_key, ovf_count);
    hipLaunchKernelGGL(brute_kernel,   dim3(BRUTE_BLOCKS), dim3(256), 0, stream,
                       P4, ovf, ovf_key, ovf_count, Cov);
    hipLaunchKernelGGL(eigh_loss_kernel, dim3(BN/256), dim3(256), 0, stream,
                       Cov, accum, counter, out);
}

// Round 18
// 325.576 us; speedup vs baseline: 1.0811x; 1.0048x over previous
//
#include <hip/hip_runtime.h>
#include <math.h>

#define BB   4
#define NN   8192
#define BN   (BB*NN)       // 32768 points per cloud-set; 8 clouds of 8192 total
#define KNN  10
#define G    32            // grid cells per dim
#define NCELLS (G*G*G)     // 32768 cells per cloud
#define GRID_LO (-5.0f)
#define H    0.3125f       // 10/32
#define INV_H 3.2f
#define RCAP 2             // rho<=2 region; beyond -> brute overflow

#define SEPS    5.9604645e-8f        // slamch('E') = 2^-24
#define SEPS2   (SEPS*SEPS)
#define SSAFMIN 1.1754944e-38f

__device__ __forceinline__ int cellc(float v) {
    int c = (int)floorf((v - GRID_LO) * INV_H);
    return min(G - 1, max(0, c));
}

// ---------------------------------------------------------------------------
// Kernel A: build P4[8][8192] = (x,y,z, bitcast orig-idx); clouds 0-3 = gt
// batches, 4-7 = pred[idx12] batches. Histogram cells + zero accumulators.
// ---------------------------------------------------------------------------
__global__ __launch_bounds__(256) void prep_kernel(
    const float* __restrict__ gt, const float* __restrict__ pred,
    const unsigned* __restrict__ idxw, float4* __restrict__ P4,
    int* __restrict__ hist, float* __restrict__ accum,
    unsigned* __restrict__ counter, int* __restrict__ ovf_count)
{
    __shared__ int s_is32;
    int tid = threadIdx.x;
    if (tid == 0) s_is32 = 0;
    __syncthreads();
    if (idxw[2*tid + 1] != 0u) s_is32 = 1;   // int64 => all high words 0
    __syncthreads();
    bool is64 = (s_is32 == 0);

    if (blockIdx.x == 0 && tid == 0) {
        *accum = 0.0f; *counter = 0u; *ovf_count = 0;
    }

    int point = blockIdx.x * 256 + tid;        // 0 .. 2*BN-1
    int pair = point >> 13;                    // 0..7
    int r    = point & (NN - 1);               // idx within cloud
    float x, y, z;
    if (point < BN) {
        const float* s = gt + (size_t)point*3;
        x = s[0]; y = s[1]; z = s[2];
    } else {
        int rr = point - BN;
        int b = rr >> 13;
        unsigned idx = is64 ? idxw[2*(size_t)rr] : idxw[rr];
        const float* s = pred + ((size_t)b*NN + idx)*3;
        x = s[0]; y = s[1]; z = s[2];
    }
    P4[point] = make_float4(x, y, z, __int_as_float(r));
    int cell = (cellc(z)*G + cellc(y))*G + cellc(x);
    atomicAdd(&hist[(size_t)pair*NCELLS + cell], 1);
}

// ---------------------------------------------------------------------------
// Kernel B: per-cloud exclusive scan -> combo[c] = int2(start, count).
// ---------------------------------------------------------------------------
__global__ __launch_bounds__(1024) void scan_kernel(
    const int* __restrict__ hist, int2* __restrict__ combo)
{
    int cloud = blockIdx.x;
    int tid = threadIdx.x;
    int lane = tid & 63, wid = tid >> 6;
    const int* h = hist + (size_t)cloud * NCELLS;
    int2* cb = combo + (size_t)cloud * NCELLS;

    int loc[32];
    int base = tid * 32;
    const int4* h4 = (const int4*)(h + base);
    int sum = 0;
    #pragma unroll
    for (int i = 0; i < 8; ++i) {
        int4 a = h4[i];
        loc[4*i+0] = a.x; loc[4*i+1] = a.y; loc[4*i+2] = a.z; loc[4*i+3] = a.w;
        sum += a.x + a.y + a.z + a.w;
    }
    // inclusive wave scan of sums
    int v = sum;
    #pragma unroll
    for (int off = 1; off < 64; off <<= 1) {
        int o = __shfl_up(v, off, 64);
        if (lane >= off) v += o;
    }
    __shared__ int ws[16], wsx[16];
    if (lane == 63) ws[wid] = v;
    __syncthreads();
    if (tid < 16) {
        int acc = 0;
        for (int i = 0; i < tid; ++i) acc += ws[i];
        wsx[tid] = acc;
    }
    __syncthreads();
    int run = (v - sum) + wsx[wid];            // exclusive prefix for this thread

    int4* cb4 = (int4*)(cb + base);            // 2 cells per int4 store
    #pragma unroll
    for (int i = 0; i < 16; ++i) {
        int4 o;
        o.x = run; o.y = loc[2*i];     run += loc[2*i];
        o.z = run; o.w = loc[2*i+1];   run += loc[2*i+1];
        cb4[i] = o;
    }
}

// ---------------------------------------------------------------------------
// Kernel C: scatter points into cell-sorted S.
// ---------------------------------------------------------------------------
__global__ __launch_bounds__(256) void scatter_kernel(
    const float4* __restrict__ P4, int* __restrict__ hist,
    const int2* __restrict__ combo, float4* __restrict__ S)
{
    int point = blockIdx.x * 256 + threadIdx.x;
    float4 p = P4[point];
    int pair = point >> 13;
    int cell = (cellc(p.z)*G + cellc(p.y))*G + cellc(p.x);
    int old = atomicSub(&hist[(size_t)pair*NCELLS + cell], 1);
    int pos = combo[(size_t)pair*NCELLS + cell].x + old - 1;
    S[(size_t)pair*NN + pos] = p;
}

// ---------------------------------------------------------------------------
// LAPACK ssyevd 3x3 path: ssytrd('L') + sorgtr + ssteqr('V'). Sign-faithful.
// (verified absmax 0.0 in rounds 2-17 — do not touch)
// ---------------------------------------------------------------------------
__device__ __forceinline__ float f_sign(float a, float b) {
    return copysignf(a, b);
}
__device__ __forceinline__ float slapy2(float x, float y) {
#pragma clang fp contract(off)
    float xa = fabsf(x), ya = fabsf(y);
    float w = fmaxf(xa, ya), z = fminf(xa, ya);
    if (z == 0.0f) return w;
    float t = z / w;
    return w * __fsqrt_rn(1.0f + t*t);
}
__device__ __forceinline__ void slartg_(float f, float g, float* cs, float* sn, float* r) {
#pragma clang fp contract(off)
    if (g == 0.0f)      { *cs = 1.0f; *sn = 0.0f; *r = f; }
    else if (f == 0.0f) { *cs = 0.0f; *sn = f_sign(1.0f, g); *r = fabsf(g); }
    else {
        float f1 = fabsf(f);
        float d = __fsqrt_rn(f*f + g*g);
        float p = 1.0f / d;
        *cs = f1 * p;
        *sn = g * f_sign(p, f);
        *r  = f_sign(d, f);
    }
}
__device__ void slaev2_(float a, float b, float c,
                        float* rt1, float* rt2, float* cs1, float* sn1) {
#pragma clang fp contract(off)
    float sm = a + c, df = a - c;
    float adf = fabsf(df);
    float tb = b + b;
    float ab = fabsf(tb);
    float acmx, acmn;
    if (fabsf(a) > fabsf(c)) { acmx = a; acmn = c; } else { acmx = c; acmn = a; }
    float rt;
    if (adf > ab)      { float t = ab/adf; rt = adf*__fsqrt_rn(1.0f + t*t); }
    else if (adf < ab) { float t = adf/ab; rt = ab*__fsqrt_rn(1.0f + t*t); }
    else               { rt = ab*__fsqrt_rn(2.0f); }
    int sgn1;
    if (sm < 0.0f)      { *rt1 = 0.5f*(sm - rt); sgn1 = -1;
                          *rt2 = (acmx / *rt1)*acmn - (b / *rt1)*b; }
    else if (sm > 0.0f) { *rt1 = 0.5f*(sm + rt); sgn1 = 1;
                          *rt2 = (acmx / *rt1)*acmn - (b / *rt1)*b; }
    else                { *rt1 = 0.5f*rt; *rt2 = -0.5f*rt; sgn1 = 1; }
    float cs; int sgn2;
    if (df >= 0.0f) { cs = df + rt; sgn2 = 1; } else { cs = df - rt; sgn2 = -1; }
    float acs = fabsf(cs);
    float c1, s1;
    if (acs > ab) { float ct = -tb/cs; s1 = 1.0f/__fsqrt_rn(1.0f + ct*ct); c1 = ct*s1; }
    else {
        if (ab == 0.0f) { c1 = 1.0f; s1 = 0.0f; }
        else { float tn = -cs/tb; c1 = 1.0f/__fsqrt_rn(1.0f + tn*tn); s1 = tn*c1; }
    }
    if (sgn1 == sgn2) { float tn = c1; c1 = -s1; s1 = tn; }
    *cs1 = c1; *sn1 = s1;
}

__device__ void eigh3_smallest(float c00, float c01, float c02,
                               float c11, float c12, float c22, float nv[3])
{
#pragma clang fp contract(off)
    // ---- ssytrd('L') ----
    float d[4], e[3], z[4][4];
    float tau1, v2 = 0.0f;
    float e1, d2, d3, e2;
    float alpha = c01, x = c02;
    if (x == 0.0f) {
        tau1 = 0.0f; e1 = alpha;
        d2 = c11; d3 = c22; e2 = c12;
    } else {
        float beta = -f_sign(slapy2(alpha, fabsf(x)), alpha);
        tau1 = (beta - alpha) / beta;
        v2 = x / (alpha - beta);
        e1 = beta;
        float w1 = tau1*(c11 + c12*v2);
        float w2 = tau1*(c12 + c22*v2);
        float al = -0.5f*tau1*(w1 + w2*v2);
        w1 = w1 + al;
        w2 = w2 + al*v2;
        d2 = (c11 - w1) - w1;
        e2 = (c12 - v2*w1) - w2;
        d3 = (c22 - v2*w2) - w2*v2;
    }
    d[1] = c00; d[2] = d2; d[3] = d3;
    e[1] = e1;  e[2] = e2;
    z[1][1] = 1.0f; z[1][2] = 0.0f; z[1][3] = 0.0f;
    z[2][1] = 0.0f; z[3][1] = 0.0f;
    z[2][2] = 1.0f - tau1;
    float mtv = -tau1*v2;
    z[2][3] = mtv; z[3][2] = mtv;
    z[3][3] = 1.0f + mtv*v2;

    // ---- ssteqr('V', 3) ----
    const int n = 3, nm1 = 2;
    int l1 = 1, jtot = 0;
    const int nmaxit = 90;
    float cw[3], sw[3];
    int guard = 0;
    while (guard++ < 64) {
        if (l1 > n) break;
        if (l1 > 1) e[l1-1] = 0.0f;
        int m = n;
        if (l1 <= nm1) {
            for (int mi = l1; mi <= nm1; ++mi) {
                float tst = fabsf(e[mi]);
                if (tst == 0.0f) { m = mi; break; }
                if (tst <= (__fsqrt_rn(fabsf(d[mi]))*__fsqrt_rn(fabsf(d[mi+1])))*SEPS) {
                    e[mi] = 0.0f; m = mi; break;
                }
            }
        }
        int l = l1;
        int lsv = l, lend = m, lendsv = lend;
        l1 = m + 1;
        if (lend == l) continue;
        if (fabsf(d[lend]) < fabsf(d[l])) { lend = lsv; l = lendsv; }

        if (lend > l) {
            // QL
            while (true) {
                int m_ = lend;
                if (l != lend) {
                    for (int mi = l; mi <= lend-1; ++mi) {
                        float em = e[mi];
                        float tst = em*em;
                        if (tst <= (SEPS2*fabsf(d[mi]))*fabsf(d[mi+1]) + SSAFMIN) { m_ = mi; break; }
                    }
                }
                if (m_ < lend) e[m_] = 0.0f;
                float p = d[l];
                if (m_ == l) {
                    d[l] = p; l = l + 1;
                    if (l <= lend) continue; else break;
                }
                if (m_ == l + 1) {
                    float rt1, rt2, cc, ss;
                    slaev2_(d[l], e[l], d[l+1], &rt1, &rt2, &cc, &ss);
                    for (int i = 1; i <= 3; ++i) {
                        float tmp = z[i][l+1];
                        z[i][l+1] = cc*tmp - ss*z[i][l];
                        z[i][l]   = ss*tmp + cc*z[i][l];
                    }
                    d[l] = rt1; d[l+1] = rt2; e[l] = 0.0f;
                    l = l + 2;
                    if (l <= lend) continue; else break;
                }
                if (jtot == nmaxit) break;
                jtot++;
                float g = (d[l+1] - p) / (2.0f*e[l]);
                float r = slapy2(g, 1.0f);
                g = d[m_] - p + (e[l] / (g + f_sign(r, g)));
                float s = 1.0f, c = 1.0f;
                p = 0.0f;
                for (int i = m_-1; i >= l; --i) {
                    float f = s*e[i];
                    float b = c*e[i];
                    slartg_(g, f, &c, &s, &r);
                    if (i != m_-1) e[i+1] = r;
                    g = d[i+1] - p;
                    r = (d[i] - g)*s + (2.0f*c)*b;
                    p = s*r;
                    d[i+1] = g + p;
                    g = c*r - b;
                    cw[i] = c; sw[i] = -s;
                }
                for (int j = m_-1; j >= l; --j) {
                    float cc = cw[j], ss = sw[j];
                    for (int i = 1; i <= 3; ++i) {
                        float tmp = z[i][j+1];
                        z[i][j+1] = cc*tmp - ss*z[i][j];
                        z[i][j]   = ss*tmp + cc*z[i][j];
                    }
                }
                d[l] = d[l] - p;
                e[l] = g;
            }
        } else {
            // QR
            while (true) {
                int m_ = lend;
                if (l != lend) {
                    for (int mi = l; mi >= lend+1; --mi) {
                        float em = e[mi-1];
                        float tst = em*em;
                        if (tst <= (SEPS2*fabsf(d[mi]))*fabsf(d[mi-1]) + SSAFMIN) { m_ = mi; break; }
                    }
                }
                if (m_ > lend) e[m_-1] = 0.0f;
                float p = d[l];
                if (m_ == l) {
                    d[l] = p; l = l - 1;
                    if (l >= lend) continue; else break;
                }
                if (m_ == l - 1) {
                    float rt1, rt2, cc, ss;
                    slaev2_(d[l-1], e[l-1], d[l], &rt1, &rt2, &cc, &ss);
                    for (int i = 1; i <= 3; ++i) {
                        float tmp = z[i][l];
                        z[i][l]   = cc*tmp - ss*z[i][l-1];
                        z[i][l-1] = ss*tmp + cc*z[i][l-1];
                    }
                    d[l-1] = rt1; d[l] = rt2; e[l-1] = 0.0f;
                    l = l - 2;
                    if (l >= lend) continue; else break;
                }
                if (jtot == nmaxit) break;
                jtot++;
                float g = (d[l-1] - p) / (2.0f*e[l-1]);
                float r = slapy2(g, 1.0f);
                g = d[m_] - p + (e[l-1] / (g + f_sign(r, g)));
                float s = 1.0f, c = 1.0f;
                p = 0.0f;
                for (int i = m_; i <= l-1; ++i) {
                    float f = s*e[i];
                    float b = c*e[i];
                    slartg_(g, f, &c, &s, &r);
                    if (i != m_) e[i-1] = r;
                    g = d[i] - p;
                    r = (d[i+1] - g)*s + (2.0f*c)*b;
                    p = s*r;
                    d[i] = g + p;
                    g = c*r - b;
                    cw[i] = c; sw[i] = s;
                }
                for (int j = m_; j <= l-1; ++j) {
                    float cc = cw[j], ss = sw[j];
                    for (int i = 1; i <= 3; ++i) {
                        float tmp = z[i][j+1];
                        z[i][j+1] = cc*tmp - ss*z[i][j];
                        z[i][j]   = ss*tmp + cc*z[i][j];
                    }
                }
                d[l] = d[l] - p;
                e[l-1] = g;
            }
        }
    }
    for (int ii = 2; ii <= 3; ++ii) {
        int i = ii - 1, k = i;
        float p = d[i];
        for (int j = ii; j <= 3; ++j) if (d[j] < p) { k = j; p = d[j]; }
        if (k != i) {
            d[k] = d[i]; d[i] = p;
            for (int r2 = 1; r2 <= 3; ++r2) {
                float t = z[r2][i]; z[r2][i] = z[r2][k]; z[r2][k] = t;
            }
        }
    }
    nv[0] = z[1][1]; nv[1] = z[2][1]; nv[2] = z[3][1];
}

// Covariance of the sorted 10-neighborhood (same op order as rounds 2-17).
__device__ void cov_compute(const float4* __restrict__ cl,
                            const unsigned long long keys[KNN], float c[6])
{
#pragma clang fp contract(off)
    float px[KNN], py[KNN], pz[KNN];
    float sx = 0.f, sy = 0.f, sz = 0.f;
    #pragma unroll
    for (int s = 0; s < KNN; ++s) {
        int ni = (int)(unsigned)(keys[s] & 0xFFFFFFFFull);
        float4 np = cl[ni];
        px[s] = np.x; py[s] = np.y; pz[s] = np.z;
        sx = sx + px[s]; sy = sy + py[s]; sz = sz + pz[s];
    }
    float mx = sx / 10.0f, my = sy / 10.0f, mz = sz / 10.0f;
    float c00=0.f,c01=0.f,c02=0.f,c11=0.f,c12=0.f,c22=0.f;
    #pragma unroll
    for (int s = 0; s < KNN; ++s) {
        float dx = px[s]-mx, dy = py[s]-my, dz = pz[s]-mz;
        c00 = c00 + dx*dx; c01 = c01 + dx*dy; c02 = c02 + dx*dz;
        c11 = c11 + dy*dy; c12 = c12 + dy*dz; c22 = c22 + dz*dz;
    }
    c[0] = c00/10.0f; c[1] = c01/10.0f; c[2] = c02/10.0f;
    c[3] = c11/10.0f; c[4] = c12/10.0f; c[5] = c22/10.0f;
}

// candidate insert (strict u64 key compare == top_k (d, idx) tie semantics)
#define PROC(p) do { \
    float ddx = qx - (p).x, ddy = qy - (p).y, ddz = qz - (p).z; \
    float dd = fmaf(ddz, ddz, fmaf(ddy, ddy, ddx*ddx)); \
    unsigned long long key = \
        ((unsigned long long)__float_as_uint(dd) << 32) | \
        (unsigned)__float_as_int((p).w); \
    if (key < k9) { \
        unsigned long long ck = key; \
        _Pragma("unroll") \
        for (int s = 0; s < KNN; ++s) { \
            unsigned long long ok2 = keys[s]; \
            bool sw = ok2 > ck; \
            keys[s] = sw ? ck : ok2; \
            ck      = sw ? ok2 : ck; \
        } \
        k9 = keys[KNN-1]; \
        worst = __uint_as_float((unsigned)(k9 >> 32)); \
    } \
} while (0)

// stream a contiguous candidate segment [b, b+n) of S — 2 loads in flight
#define SEGPROC(b, n) do { \
    int _j = (b), _je = (b) + (n); \
    for (; _j + 2 <= _je; _j += 2) { \
        float4 _p0 = cs[_j]; float4 _p1 = cs[_j+1]; \
        PROC(_p0); PROC(_p1); \
    } \
    if (_j < _je) { float4 _p0 = cs[_j]; PROC(_p0); } \
} while (0)

// 4-way compile-time coordinate select (3 cndmasks, once per slot)
#define SEL4(A,B,C,D) (sub == 0 ? (A) : (sub == 1 ? (B) : (sub == 2 ? (C) : (D))))

// ---------------------------------------------------------------------------
// Kernel D (R18): grid 10-NN, FOUR lanes per query, walk partitioned by
// compile-time 4-way checkerboard (R16/R17's verified principle, deeper).
// Per-lane slots: 3 cube rows + 4 shell rows + 5 cells = 12 (vs 22 at 2-way).
// Exactness: per-lane strict-u64 subset top-10s; pruning bound = fmin over
// the 4 lane 10ths (each >= global 10th by subset property; fminf NaN-skip
// verified R16/R17); 2-round width-4 shfl_xor merge -> exact sorted global
// top-10; resolved test on merged 10th -> identical overflow set.
// ---------------------------------------------------------------------------
__global__ __launch_bounds__(256) void knn_main_kernel(
    const float4* __restrict__ P4, const float4* __restrict__ S,
    const int2* __restrict__ combo, float4* __restrict__ Cov,
    int* __restrict__ ovf, unsigned long long* __restrict__ ovf_key,
    int* __restrict__ ovf_count)
{
    int tidg = blockIdx.x * 256 + threadIdx.x;  // 0..262143
    int qid  = tidg >> 2;                       // 0..65535
    int sub  = tidg & 3;
    int pair = qid >> 13;                       // 8 clouds
    int spos = qid & (NN - 1);                  // sorted position
    const float4* __restrict__ cl = P4 + (size_t)pair * NN;
    const float4* __restrict__ cs = S  + (size_t)pair * NN;
    const int2*   __restrict__ cb = combo + (size_t)pair * NCELLS;

    float4 q = cs[spos];
    float qx = q.x, qy = q.y, qz = q.z;
    int qi = __float_as_int(q.w);               // original index in cloud
    int qcx = cellc(qx), qcy = cellc(qy), qcz = cellc(qz);

    unsigned long long keys[KNN];
    #pragma unroll
    for (int s = 0; s < KNN; ++s) keys[s] = 0xFFFFFFFFFFFFFFFFull;
    unsigned long long k9 = keys[KNN-1];
    float worst = __uint_as_float(0xFFFFFFFFu); // NaN: all strict-> tests false

    // ---- phase 1: rho<=1 cube, 9 rows checkerboarded 3/2/2/2 ----
    int x0 = max(qcx - 1, 0), x1 = min(qcx + 1, G - 1);
#define P1SLOT(i, ZA,YA, ZB,YB, ZC,YC, ZD,YD) \
    int rb##i = 0, re##i = 0; \
    { int zz = qcz + SEL4(ZA,ZB,ZC,ZD); \
      int yy = qcy + SEL4(YA,YB,YC,YD); \
      if ((unsigned)zz < G && (unsigned)yy < G) { \
          int cbase = (zz*G + yy)*G; \
          int2 a = cb[cbase + x0]; \
          int2 b = cb[cbase + x1]; \
          rb##i = a.x; re##i = b.x + b.y; } }
    P1SLOT(0, -1,-1, -1,0, -1,1, 0,-1)
    P1SLOT(1,  0, 0,  0,1,  1,-1, 1, 0)
    P1SLOT(2,  1, 1, 99,99, 99,99, 99,99)   // lanes 1-3 invalid -> bounds fail
#undef P1SLOT
#define P1GO(i) SEGPROC(rb##i, re##i - rb##i);
    P1GO(0) P1GO(1) P1GO(2)
#undef P1GO

    // ---- exchange: shared bound = min of 4 lane 10ths (NaN = missing) ----
    float bshared = worst;
    {
        unsigned w1 = (unsigned)__shfl_xor((int)(unsigned)(k9 >> 32), 1, 4);
        bshared = fminf(bshared, __uint_as_float(w1));
        unsigned b32 = __float_as_uint(bshared);
        unsigned w2 = (unsigned)__shfl_xor((int)b32, 2, 4);
        bshared = fminf(bshared, __uint_as_float(w2));
    }

    // ---- phase 2: rho=2 shell (skip iff H^2 > bshared; conservative) ----
    bool skip = (H*H > bshared);                // NaN-safe: NaN -> walk shell
    {
        int xs0 = max(qcx - 2, 0), xs1 = min(qcx + 2, G - 1);
        // 16 outer rows, checkerboarded 4/4/4/4
#define S2SLOT(i, ZA,YA, ZB,YB, ZC,YC, ZD,YD) \
        int sb##i = 0, sn##i = 0; \
        if (!skip) { \
          int zz = qcz + SEL4(ZA,ZB,ZC,ZD); \
          int yy = qcy + SEL4(YA,YB,YC,YD); \
          if ((unsigned)zz < G && (unsigned)yy < G) { \
              float loy = fmaf((float)yy, H, GRID_LO); \
              float loz = fmaf((float)zz, H, GRID_LO); \
              float py = fmaxf(0.0f, fmaxf(loy - qy, qy - (loy + H))); \
              float pz = fmaxf(0.0f, fmaxf(loz - qz, qz - (loz + H))); \
              float pyz = fmaf(pz, pz, py*py); \
              float pw = fminf(worst, bshared); \
              if (!(pyz > pw)) { \
                  int cbase = (zz*G + yy)*G; \
                  int2 a = cb[cbase + xs0]; \
                  int2 b = cb[cbase + xs1]; \
                  sb##i = a.x; sn##i = (b.x + b.y) - a.x; } } }
        S2SLOT(0, -2,-2, -2,-1, -2,0, -2,1)
        S2SLOT(1, -2, 2,  2,-2,  2,-1, 2,0)
        S2SLOT(2,  2, 1,  2, 2, -1,-2, -1,2)
        S2SLOT(3,  0,-2,  0, 2,  1,-2,  1,2)
#undef S2SLOT
        // 18 isolated cells (|dz|<=1,|dy|<=1, dx=+/-2), 5 slots x 4 lanes
#define CSLOT(i, ZA,YA,XA, ZB,YB,XB, ZC,YC,XC, ZD,YD,XD) \
        int tb##i = 0, tn##i = 0; \
        if (!skip) { \
          int zz = qcz + SEL4(ZA,ZB,ZC,ZD); \
          int yy = qcy + SEL4(YA,YB,YC,YD); \
          int xx = qcx + SEL4(XA,XB,XC,XD); \
          if ((unsigned)zz < G && (unsigned)yy < G && (unsigned)xx < G) { \
              float lox = fmaf((float)xx, H, GRID_LO); \
              float loy = fmaf((float)yy, H, GRID_LO); \
              float loz = fmaf((float)zz, H, GRID_LO); \
              float px = fmaxf(0.0f, fmaxf(lox - qx, qx - (lox + H))); \
              float py = fmaxf(0.0f, fmaxf(loy - qy, qy - (loy + H))); \
              float pz = fmaxf(0.0f, fmaxf(loz - qz, qz - (loz + H))); \
              float m2 = fmaf(pz, pz, fmaf(py, py, px*px)); \
              float pw = fminf(worst, bshared); \
              if (!(m2 > pw)) { \
                  int2 a = cb[(zz*G + yy)*G + xx]; \
                  tb##i = a.x; tn##i = a.y; } } }
        CSLOT(0, -1,-1,-2, -1,-1,2, -1,0,-2, -1,0,2)
        CSLOT(1, -1, 1,-2, -1, 1,2,  0,-1,-2, 0,-1,2)
        CSLOT(2,  0, 0,-2,  0, 0,2,  0, 1,-2, 0, 1,2)
        CSLOT(3,  1,-1,-2,  1,-1,2,  1, 0,-2, 1, 0,2)
        CSLOT(4,  1, 1,-2,  1, 1,2, 99,99,0, 99,99,0)
#undef CSLOT
#define S2GO(i) SEGPROC(sb##i, sn##i);
        S2GO(0) S2GO(1) S2GO(2) S2GO(3)
#undef S2GO
#define CGO(i) SEGPROC(tb##i, tn##i);
        CGO(0) CGO(1) CGO(2) CGO(3) CGO(4)
#undef CGO
    }

    // ---- merge the 4 per-lane sorted lists -> exact global top-10 ----
    #pragma unroll
    for (int m = 1; m < 4; m <<= 1) {
        unsigned long long other[KNN];
        #pragma unroll
        for (int s = 0; s < KNN; ++s)
            other[s] = __shfl_xor(keys[s], m, 4);   // snapshot before inserts
        #pragma unroll
        for (int s = 0; s < KNN; ++s) {
            unsigned long long key = other[s];
            if (key < k9) {
                unsigned long long ck = key;
                #pragma unroll
                for (int t = 0; t < KNN; ++t) {
                    unsigned long long ok2 = keys[t];
                    bool sw = ok2 > ck;
                    keys[t] = sw ? ck : ok2;
                    ck      = sw ? ok2 : ck;
                }
                k9 = keys[KNN-1];
            }
        }
    }
    float worst_m = __uint_as_float((unsigned)(k9 >> 32));

    // resolved iff cells beyond the rho<=2 region (gap >= 2H) cannot contribute
    float bf = (float)RCAP * H;
    bool resolved = (bf*bf > worst_m);          // strict; NaN (unfilled) -> false
    if (resolved) {
        float c[6];
        cov_compute(cl, keys, c);               // all 4 lanes (cheap, no eigh)
        if (sub == 0) {
            size_t o = ((size_t)pair*NN + qi)*2;
            Cov[o]   = make_float4(c[0], c[1], c[2], c[3]);
            Cov[o+1] = make_float4(c[4], c[5], 0.0f, 0.0f);
        }
    } else if (sub == 0) {
        int pos = atomicAdd(ovf_count, 1);
        ovf[pos] = (pair << 13) | qi;
        ovf_key[pos] = k9;      // merged 10th-best: valid upper bound on true
    }                           // 10th key (subset 10th >= full-set 10th)
}

// ---------------------------------------------------------------------------
// Kernel D2: brute-force overflow (R14 config), one query per block. Bound
// gate skips the insert chain for provably-excluded candidates. Writes
// covariance (eigh relocated to eigh_loss).
// ---------------------------------------------------------------------------
#define BRUTE_BLOCKS 4096
__global__ __launch_bounds__(256) void brute_kernel(
    const float4* __restrict__ P4, const int* __restrict__ ovf,
    const unsigned long long* __restrict__ ovf_key,
    const int* __restrict__ ovf_count, float4* __restrict__ Cov)
{
    __shared__ unsigned long long wl[4][KNN];
    int tid = threadIdx.x;
    int lane = tid & 63;
    int wid = tid >> 6;
    int count = *ovf_count;

    for (int oi = blockIdx.x; oi < count; oi += BRUTE_BLOCKS) {
        int rec = ovf[oi];
        unsigned long long bound = ovf_key[oi];
        float bound_d = __uint_as_float((unsigned)(bound >> 32)); // NaN if unfilled
        int pair = rec >> 13;
        int qi = rec & (NN - 1);
        const float4* __restrict__ cl = P4 + (size_t)pair * NN;
        float4 q = cl[qi];
        float qx = q.x, qy = q.y, qz = q.z;

        unsigned long long keys[KNN];
        #pragma unroll
        for (int s = 0; s < KNN; ++s) keys[s] = 0xFFFFFFFFFFFFFFFFull;
        unsigned long long k9 = keys[KNN-1];

        // per-lane scan with bound gate; ties at dd==bound_d pass (exact)
#define BPROC(p, jj) do { \
        float ddx = qx - (p).x, ddy = qy - (p).y, ddz = qz - (p).z; \
        float dd = fmaf(ddz, ddz, fmaf(ddy, ddy, ddx*ddx)); \
        if (!(dd > bound_d)) { \
            unsigned long long key = \
                ((unsigned long long)__float_as_uint(dd) << 32) | (unsigned)(jj); \
            if (key < k9) { \
                unsigned long long ck = key; \
                _Pragma("unroll") \
                for (int s = 0; s < KNN; ++s) { \
                    unsigned long long ok2 = keys[s]; \
                    bool sw = ok2 > ck; \
                    keys[s] = sw ? ck : ok2; \
                    ck      = sw ? ok2 : ck; \
                } \
                k9 = keys[KNN-1]; \
            } \
        } \
    } while (0)
        #pragma unroll 1
        for (int j = tid; j < NN; j += 1024) {  // 8 iterations, 4 loads each
            float4 p0 = cl[j];
            float4 p1 = cl[j + 256];
            float4 p2 = cl[j + 512];
            float4 p3 = cl[j + 768];
            BPROC(p0, j);
            BPROC(p1, j + 256);
            BPROC(p2, j + 512);
            BPROC(p3, j + 768);
        }
#undef BPROC

        // in-wave tree merge -> every lane holds its wave's top-10
        #pragma unroll
        for (int m = 1; m < 64; m <<= 1) {
            unsigned long long other[KNN];
            #pragma unroll
            for (int s = 0; s < KNN; ++s)
                other[s] = __shfl_xor(keys[s], m);  // snapshot before inserts
            #pragma unroll
            for (int s = 0; s < KNN; ++s) {
                unsigned long long key = other[s];
                if (key < k9) {
                    unsigned long long ck = key;
                    #pragma unroll
                    for (int t = 0; t < KNN; ++t) {
                        unsigned long long ok2 = keys[t];
                        bool sw = ok2 > ck;
                        keys[t] = sw ? ck : ok2;
                        ck      = sw ? ok2 : ck;
                    }
                    k9 = keys[KNN-1];
                }
            }
        }

        // cross-wave merge via LDS (4 sorted lists)
        if (lane == 0) {
            #pragma unroll
            for (int s = 0; s < KNN; ++s) wl[wid][s] = keys[s];
        }
        __syncthreads();
        if (wid == 0) {
            for (int w2 = 1; w2 < 4; ++w2) {
                #pragma unroll
                for (int s = 0; s < KNN; ++s) {
                    unsigned long long key = wl[w2][s];
                    if (key >= k9) break;       // lists sorted ascending
                    unsigned long long ck = key;
                    #pragma unroll
                    for (int t = 0; t < KNN; ++t) {
                        unsigned long long ok2 = keys[t];
                        bool sw = ok2 > ck;
                        keys[t] = sw ? ck : ok2;
                        ck      = sw ? ok2 : ck;
                    }
                    k9 = keys[KNN-1];
                }
            }
            if (lane == 0) {
                float c[6];
                cov_compute(cl, keys, c);
                size_t o = ((size_t)pair*NN + qi)*2;
                Cov[o]   = make_float4(c[0], c[1], c[2], c[3]);
                Cov[o+1] = make_float4(c[4], c[5], 0.0f, 0.0f);
            }
        }
        __syncthreads();                        // protect wl for next query
    }
}

// ---------------------------------------------------------------------------
// Kernel E: fused eigh + loss. One thread per point pair: two eighs
// (identical inputs to the old in-kernel eighs -> bit-identical normals),
// then 1 - cos, block reduce, atomic accumulate.
// ---------------------------------------------------------------------------
__global__ __launch_bounds__(256) void eigh_loss_kernel(
    const float4* __restrict__ Cov, float* __restrict__ accum,
    unsigned* __restrict__ counter, float* __restrict__ out)
{
    int tid = threadIdx.x;
    int i = blockIdx.x * 256 + tid;            // 0..BN-1
    float4 a0 = Cov[(size_t)i*2],            a1 = Cov[(size_t)i*2 + 1];
    float4 b0 = Cov[((size_t)BN + i)*2],     b1 = Cov[((size_t)BN + i)*2 + 1];
    float gn[3], pn[3];
    eigh3_smallest(a0.x, a0.y, a0.z, a0.w, a1.x, a1.y, gn);
    eigh3_smallest(b0.x, b0.y, b0.z, b0.w, b1.x, b1.y, pn);

    float gx=gn[0], gy=gn[1], gz=gn[2];
    float hx=pn[0], hy=pn[1], hz=pn[2];
    float dot = fmaf(gx,hx,fmaf(gy,hy,gz*hz));
    float ng  = sqrtf(fmaf(gx,gx,fmaf(gy,gy,gz*gz)));
    float nh  = sqrtf(fmaf(hx,hx,fmaf(hy,hy,hz*hz)));
    float den = fmaxf(ng*nh, 1e-8f);
    float v = 1.0f - dot/den;

    __shared__ float red[256];
    red[tid] = v;
    __syncthreads();
    for (int s = 128; s > 0; s >>= 1) {
        if (tid < s) red[tid] += red[tid+s];
        __syncthreads();
    }
    if (tid == 0) {
        atomicAdd(accum, red[0]);
        __threadfence();
        unsigned old = atomicAdd(counter, 1u);
        if (old == (unsigned)(BN/256 - 1)) {
            float tot = atomicAdd(accum, 0.0f);
            out[0] = tot * (1.0f/(float)BN);
        }
    }
}

// ---------------------------------------------------------------------------
extern "C" void kernel_launch(void* const* d_in, const int* in_sizes, int n_in,
                              void* d_out, int out_size, void* d_ws, size_t ws_size,
                              hipStream_t stream)
{
    (void)in_sizes; (void)n_in; (void)out_size; (void)ws_size;
    const float*    gt   = (const float*)d_in[0];
    const float*    pred = (const float*)d_in[1];
    const unsigned* idxw = (const unsigned*)d_in[2];
    float* out = (float*)d_out;

    char* w = (char*)d_ws;
    float4* P4   = (float4*)w;                         w += (size_t)2*BN*16;   // 1 MB
    float4* S    = (float4*)w;                         w += (size_t)2*BN*16;   // 1 MB
    int*    hist = (int*)w;                            w += (size_t)8*NCELLS*4;   // 1 MB
    int2*   combo = (int2*)w;                          w += (size_t)8*NCELLS*8;   // 2 MB
    float4* Cov  = (float4*)w;                         w += (size_t)2*BN*32;   // 2 MB
    float*  accum = (float*)w;                         w += 16;
    unsigned* counter = (unsigned*)(accum + 1);
    int*    ovf_count = (int*)(accum + 2);
    int*    ovf  = (int*)w;                            w += (size_t)2*BN*4;    // 0.25 MB
    unsigned long long* ovf_key = (unsigned long long*)w;  w += (size_t)2*BN*8; // 0.5 MB

    hipMemsetAsync(hist, 0, (size_t)8*NCELLS*4, stream);
    hipLaunchKernelGGL(prep_kernel,    dim3(2*BN/256), dim3(256),  0, stream,
                       gt, pred, idxw, P4, hist, accum, counter, ovf_count);
    hipLaunchKernelGGL(scan_kernel,    dim3(8),        dim3(1024), 0, stream,
                       hist, combo);
    hipLaunchKernelGGL(scatter_kernel, dim3(2*BN/256), dim3(256),  0, stream,
                       P4, hist, combo, S);
    hipLaunchKernelGGL(knn_main_kernel, dim3(2*BN*4/256), dim3(256), 0, stream,
                       P4, S, combo, Cov, ovf, ovf_key, ovf_count);
    hipLaunchKernelGGL(brute_kernel,   dim3(BRUTE_BLOCKS), dim3(256), 0, stream,
                       P4, ovf, ovf_key, ovf_count, Cov);
    hipLaunchKernelGGL(eigh_loss_kernel, dim3(BN/256), dim3(256), 0, stream,
                       Cov, accum, counter, out);
}

// Round 19
// 299.405 us; speedup vs baseline: 1.1756x; 1.0874x over previous
//
#include <hip/hip_runtime.h>
#include <math.h>

#define BB   4
#define NN   8192
#define BN   (BB*NN)       // 32768 points per cloud-set; 8 clouds of 8192 total
#define KNN  10
#define G    32            // grid cells per dim
#define NCELLS (G*G*G)     // 32768 cells per cloud
#define GRID_LO (-5.0f)
#define H    0.3125f       // 10/32
#define INV_H 3.2f
#define RCAP 2             // rho<=2 region; beyond -> brute overflow

#define SEPS    5.9604645e-8f        // slamch('E') = 2^-24
#define SEPS2   (SEPS*SEPS)
#define SSAFMIN 1.1754944e-38f

__device__ __forceinline__ int cellc(float v) {
    int c = (int)floorf((v - GRID_LO) * INV_H);
    return min(G - 1, max(0, c));
}

// ---------------------------------------------------------------------------
// Kernel A: build P4[8][8192] = (x,y,z, bitcast orig-idx); clouds 0-3 = gt
// batches, 4-7 = pred[idx12] batches. Histogram cells + zero accumulators.
// ---------------------------------------------------------------------------
__global__ __launch_bounds__(256) void prep_kernel(
    const float* __restrict__ gt, const float* __restrict__ pred,
    const unsigned* __restrict__ idxw, float4* __restrict__ P4,
    int* __restrict__ hist, float* __restrict__ accum,
    unsigned* __restrict__ counter, int* __restrict__ ovf_count)
{
    __shared__ int s_is32;
    int tid = threadIdx.x;
    if (tid == 0) s_is32 = 0;
    __syncthreads();
    if (idxw[2*tid + 1] != 0u) s_is32 = 1;   // int64 => all high words 0
    __syncthreads();
    bool is64 = (s_is32 == 0);

    if (blockIdx.x == 0 && tid == 0) {
        *accum = 0.0f; *counter = 0u; *ovf_count = 0;
    }

    int point = blockIdx.x * 256 + tid;        // 0 .. 2*BN-1
    int pair = point >> 13;                    // 0..7
    int r    = point & (NN - 1);               // idx within cloud
    float x, y, z;
    if (point < BN) {
        const float* s = gt + (size_t)point*3;
        x = s[0]; y = s[1]; z = s[2];
    } else {
        int rr = point - BN;
        int b = rr >> 13;
        unsigned idx = is64 ? idxw[2*(size_t)rr] : idxw[rr];
        const float* s = pred + ((size_t)b*NN + idx)*3;
        x = s[0]; y = s[1]; z = s[2];
    }
    P4[point] = make_float4(x, y, z, __int_as_float(r));
    int cell = (cellc(z)*G + cellc(y))*G + cellc(x);
    atomicAdd(&hist[(size_t)pair*NCELLS + cell], 1);
}

// ---------------------------------------------------------------------------
// Kernel B: per-cloud exclusive scan -> combo[c] = int2(start, count).
// ---------------------------------------------------------------------------
__global__ __launch_bounds__(1024) void scan_kernel(
    const int* __restrict__ hist, int2* __restrict__ combo)
{
    int cloud = blockIdx.x;
    int tid = threadIdx.x;
    int lane = tid & 63, wid = tid >> 6;
    const int* h = hist + (size_t)cloud * NCELLS;
    int2* cb = combo + (size_t)cloud * NCELLS;

    int loc[32];
    int base = tid * 32;
    const int4* h4 = (const int4*)(h + base);
    int sum = 0;
    #pragma unroll
    for (int i = 0; i < 8; ++i) {
        int4 a = h4[i];
        loc[4*i+0] = a.x; loc[4*i+1] = a.y; loc[4*i+2] = a.z; loc[4*i+3] = a.w;
        sum += a.x + a.y + a.z + a.w;
    }
    // inclusive wave scan of sums
    int v = sum;
    #pragma unroll
    for (int off = 1; off < 64; off <<= 1) {
        int o = __shfl_up(v, off, 64);
        if (lane >= off) v += o;
    }
    __shared__ int ws[16], wsx[16];
    if (lane == 63) ws[wid] = v;
    __syncthreads();
    if (tid < 16) {
        int acc = 0;
        for (int i = 0; i < tid; ++i) acc += ws[i];
        wsx[tid] = acc;
    }
    __syncthreads();
    int run = (v - sum) + wsx[wid];            // exclusive prefix for this thread

    int4* cb4 = (int4*)(cb + base);            // 2 cells per int4 store
    #pragma unroll
    for (int i = 0; i < 16; ++i) {
        int4 o;
        o.x = run; o.y = loc[2*i];     run += loc[2*i];
        o.z = run; o.w = loc[2*i+1];   run += loc[2*i+1];
        cb4[i] = o;
    }
}

// ---------------------------------------------------------------------------
// Kernel C: scatter points into cell-sorted S.
// ---------------------------------------------------------------------------
__global__ __launch_bounds__(256) void scatter_kernel(
    const float4* __restrict__ P4, int* __restrict__ hist,
    const int2* __restrict__ combo, float4* __restrict__ S)
{
    int point = blockIdx.x * 256 + threadIdx.x;
    float4 p = P4[point];
    int pair = point >> 13;
    int cell = (cellc(p.z)*G + cellc(p.y))*G + cellc(p.x);
    int old = atomicSub(&hist[(size_t)pair*NCELLS + cell], 1);
    int pos = combo[(size_t)pair*NCELLS + cell].x + old - 1;
    S[(size_t)pair*NN + pos] = p;
}

// ---------------------------------------------------------------------------
// LAPACK ssyevd 3x3 path: ssytrd('L') + sorgtr + ssteqr('V'). Sign-faithful.
// (verified absmax 0.0 in rounds 2-18 — do not touch)
// ---------------------------------------------------------------------------
__device__ __forceinline__ float f_sign(float a, float b) {
    return copysignf(a, b);
}
__device__ __forceinline__ float slapy2(float x, float y) {
#pragma clang fp contract(off)
    float xa = fabsf(x), ya = fabsf(y);
    float w = fmaxf(xa, ya), z = fminf(xa, ya);
    if (z == 0.0f) return w;
    float t = z / w;
    return w * __fsqrt_rn(1.0f + t*t);
}
__device__ __forceinline__ void slartg_(float f, float g, float* cs, float* sn, float* r) {
#pragma clang fp contract(off)
    if (g == 0.0f)      { *cs = 1.0f; *sn = 0.0f; *r = f; }
    else if (f == 0.0f) { *cs = 0.0f; *sn = f_sign(1.0f, g); *r = fabsf(g); }
    else {
        float f1 = fabsf(f);
        float d = __fsqrt_rn(f*f + g*g);
        float p = 1.0f / d;
        *cs = f1 * p;
        *sn = g * f_sign(p, f);
        *r  = f_sign(d, f);
    }
}
__device__ void slaev2_(float a, float b, float c,
                        float* rt1, float* rt2, float* cs1, float* sn1) {
#pragma clang fp contract(off)
    float sm = a + c, df = a - c;
    float adf = fabsf(df);
    float tb = b + b;
    float ab = fabsf(tb);
    float acmx, acmn;
    if (fabsf(a) > fabsf(c)) { acmx = a; acmn = c; } else { acmx = c; acmn = a; }
    float rt;
    if (adf > ab)      { float t = ab/adf; rt = adf*__fsqrt_rn(1.0f + t*t); }
    else if (adf < ab) { float t = adf/ab; rt = ab*__fsqrt_rn(1.0f + t*t); }
    else               { rt = ab*__fsqrt_rn(2.0f); }
    int sgn1;
    if (sm < 0.0f)      { *rt1 = 0.5f*(sm - rt); sgn1 = -1;
                          *rt2 = (acmx / *rt1)*acmn - (b / *rt1)*b; }
    else if (sm > 0.0f) { *rt1 = 0.5f*(sm + rt); sgn1 = 1;
                          *rt2 = (acmx / *rt1)*acmn - (b / *rt1)*b; }
    else                { *rt1 = 0.5f*rt; *rt2 = -0.5f*rt; sgn1 = 1; }
    float cs; int sgn2;
    if (df >= 0.0f) { cs = df + rt; sgn2 = 1; } else { cs = df - rt; sgn2 = -1; }
    float acs = fabsf(cs);
    float c1, s1;
    if (acs > ab) { float ct = -tb/cs; s1 = 1.0f/__fsqrt_rn(1.0f + ct*ct); c1 = ct*s1; }
    else {
        if (ab == 0.0f) { c1 = 1.0f; s1 = 0.0f; }
        else { float tn = -cs/tb; c1 = 1.0f/__fsqrt_rn(1.0f + tn*tn); s1 = tn*c1; }
    }
    if (sgn1 == sgn2) { float tn = c1; c1 = -s1; s1 = tn; }
    *cs1 = c1; *sn1 = s1;
}

__device__ void eigh3_smallest(float c00, float c01, float c02,
                               float c11, float c12, float c22, float nv[3])
{
#pragma clang fp contract(off)
    // ---- ssytrd('L') ----
    float d[4], e[3], z[4][4];
    float tau1, v2 = 0.0f;
    float e1, d2, d3, e2;
    float alpha = c01, x = c02;
    if (x == 0.0f) {
        tau1 = 0.0f; e1 = alpha;
        d2 = c11; d3 = c22; e2 = c12;
    } else {
        float beta = -f_sign(slapy2(alpha, fabsf(x)), alpha);
        tau1 = (beta - alpha) / beta;
        v2 = x / (alpha - beta);
        e1 = beta;
        float w1 = tau1*(c11 + c12*v2);
        float w2 = tau1*(c12 + c22*v2);
        float al = -0.5f*tau1*(w1 + w2*v2);
        w1 = w1 + al;
        w2 = w2 + al*v2;
        d2 = (c11 - w1) - w1;
        e2 = (c12 - v2*w1) - w2;
        d3 = (c22 - v2*w2) - w2*v2;
    }
    d[1] = c00; d[2] = d2; d[3] = d3;
    e[1] = e1;  e[2] = e2;
    z[1][1] = 1.0f; z[1][2] = 0.0f; z[1][3] = 0.0f;
    z[2][1] = 0.0f; z[3][1] = 0.0f;
    z[2][2] = 1.0f - tau1;
    float mtv = -tau1*v2;
    z[2][3] = mtv; z[3][2] = mtv;
    z[3][3] = 1.0f + mtv*v2;

    // ---- ssteqr('V', 3) ----
    const int n = 3, nm1 = 2;
    int l1 = 1, jtot = 0;
    const int nmaxit = 90;
    float cw[3], sw[3];
    int guard = 0;
    while (guard++ < 64) {
        if (l1 > n) break;
        if (l1 > 1) e[l1-1] = 0.0f;
        int m = n;
        if (l1 <= nm1) {
            for (int mi = l1; mi <= nm1; ++mi) {
                float tst = fabsf(e[mi]);
                if (tst == 0.0f) { m = mi; break; }
                if (tst <= (__fsqrt_rn(fabsf(d[mi]))*__fsqrt_rn(fabsf(d[mi+1])))*SEPS) {
                    e[mi] = 0.0f; m = mi; break;
                }
            }
        }
        int l = l1;
        int lsv = l, lend = m, lendsv = lend;
        l1 = m + 1;
        if (lend == l) continue;
        if (fabsf(d[lend]) < fabsf(d[l])) { lend = lsv; l = lendsv; }

        if (lend > l) {
            // QL
            while (true) {
                int m_ = lend;
                if (l != lend) {
                    for (int mi = l; mi <= lend-1; ++mi) {
                        float em = e[mi];
                        float tst = em*em;
                        if (tst <= (SEPS2*fabsf(d[mi]))*fabsf(d[mi+1]) + SSAFMIN) { m_ = mi; break; }
                    }
                }
                if (m_ < lend) e[m_] = 0.0f;
                float p = d[l];
                if (m_ == l) {
                    d[l] = p; l = l + 1;
                    if (l <= lend) continue; else break;
                }
                if (m_ == l + 1) {
                    float rt1, rt2, cc, ss;
                    slaev2_(d[l], e[l], d[l+1], &rt1, &rt2, &cc, &ss);
                    for (int i = 1; i <= 3; ++i) {
                        float tmp = z[i][l+1];
                        z[i][l+1] = cc*tmp - ss*z[i][l];
                        z[i][l]   = ss*tmp + cc*z[i][l];
                    }
                    d[l] = rt1; d[l+1] = rt2; e[l] = 0.0f;
                    l = l + 2;
                    if (l <= lend) continue; else break;
                }
                if (jtot == nmaxit) break;
                jtot++;
                float g = (d[l+1] - p) / (2.0f*e[l]);
                float r = slapy2(g, 1.0f);
                g = d[m_] - p + (e[l] / (g + f_sign(r, g)));
                float s = 1.0f, c = 1.0f;
                p = 0.0f;
                for (int i = m_-1; i >= l; --i) {
                    float f = s*e[i];
                    float b = c*e[i];
                    slartg_(g, f, &c, &s, &r);
                    if (i != m_-1) e[i+1] = r;
                    g = d[i+1] - p;
                    r = (d[i] - g)*s + (2.0f*c)*b;
                    p = s*r;
                    d[i+1] = g + p;
                    g = c*r - b;
                    cw[i] = c; sw[i] = -s;
                }
                for (int j = m_-1; j >= l; --j) {
                    float cc = cw[j], ss = sw[j];
                    for (int i = 1; i <= 3; ++i) {
                        float tmp = z[i][j+1];
                        z[i][j+1] = cc*tmp - ss*z[i][j];
                        z[i][j]   = ss*tmp + cc*z[i][j];
                    }
                }
                d[l] = d[l] - p;
                e[l] = g;
            }
        } else {
            // QR
            while (true) {
                int m_ = lend;
                if (l != lend) {
                    for (int mi = l; mi >= lend+1; --mi) {
                        float em = e[mi-1];
                        float tst = em*em;
                        if (tst <= (SEPS2*fabsf(d[mi]))*fabsf(d[mi-1]) + SSAFMIN) { m_ = mi; break; }
                    }
                }
                if (m_ > lend) e[m_-1] = 0.0f;
                float p = d[l];
                if (m_ == l) {
                    d[l] = p; l = l - 1;
                    if (l >= lend) continue; else break;
                }
                if (m_ == l - 1) {
                    float rt1, rt2, cc, ss;
                    slaev2_(d[l-1], e[l-1], d[l], &rt1, &rt2, &cc, &ss);
                    for (int i = 1; i <= 3; ++i) {
                        float tmp = z[i][l];
                        z[i][l]   = cc*tmp - ss*z[i][l-1];
                        z[i][l-1] = ss*tmp + cc*z[i][l-1];
                    }
                    d[l-1] = rt1; d[l] = rt2; e[l-1] = 0.0f;
                    l = l - 2;
                    if (l >= lend) continue; else break;
                }
                if (jtot == nmaxit) break;
                jtot++;
                float g = (d[l-1] - p) / (2.0f*e[l-1]);
                float r = slapy2(g, 1.0f);
                g = d[m_] - p + (e[l-1] / (g + f_sign(r, g)));
                float s = 1.0f, c = 1.0f;
                p = 0.0f;
                for (int i = m_; i <= l-1; ++i) {
                    float f = s*e[i];
                    float b = c*e[i];
                    slartg_(g, f, &c, &s, &r);
                    if (i != m_) e[i-1] = r;
                    g = d[i] - p;
                    r = (d[i+1] - g)*s + (2.0f*c)*b;
                    p = s*r;
                    d[i] = g + p;
                    g = c*r - b;
                    cw[i] = c; sw[i] = s;
                }
                for (int j = m_; j <= l-1; ++j) {
                    float cc = cw[j], ss = sw[j];
                    for (int i = 1; i <= 3; ++i) {
                        float tmp = z[i][j+1];
                        z[i][j+1] = cc*tmp - ss*z[i][j];
                        z[i][j]   = ss*tmp + cc*z[i][j];
                    }
                }
                d[l] = d[l] - p;
                e[l-1] = g;
            }
        }
    }
    for (int ii = 2; ii <= 3; ++ii) {
        int i = ii - 1, k = i;
        float p = d[i];
        for (int j = ii; j <= 3; ++j) if (d[j] < p) { k = j; p = d[j]; }
        if (k != i) {
            d[k] = d[i]; d[i] = p;
            for (int r2 = 1; r2 <= 3; ++r2) {
                float t = z[r2][i]; z[r2][i] = z[r2][k]; z[r2][k] = t;
            }
        }
    }
    nv[0] = z[1][1]; nv[1] = z[2][1]; nv[2] = z[3][1];
}

// Covariance of the sorted 10-neighborhood (same op order as rounds 2-18).
__device__ void cov_compute(const float4* __restrict__ cl,
                            const unsigned long long keys[KNN], float c[6])
{
#pragma clang fp contract(off)
    float px[KNN], py[KNN], pz[KNN];
    float sx = 0.f, sy = 0.f, sz = 0.f;
    #pragma unroll
    for (int s = 0; s < KNN; ++s) {
        int ni = (int)(unsigned)(keys[s] & 0xFFFFFFFFull);
        float4 np = cl[ni];
        px[s] = np.x; py[s] = np.y; pz[s] = np.z;
        sx = sx + px[s]; sy = sy + py[s]; sz = sz + pz[s];
    }
    float mx = sx / 10.0f, my = sy / 10.0f, mz = sz / 10.0f;
    float c00=0.f,c01=0.f,c02=0.f,c11=0.f,c12=0.f,c22=0.f;
    #pragma unroll
    for (int s = 0; s < KNN; ++s) {
        float dx = px[s]-mx, dy = py[s]-my, dz = pz[s]-mz;
        c00 = c00 + dx*dx; c01 = c01 + dx*dy; c02 = c02 + dx*dz;
        c11 = c11 + dy*dy; c12 = c12 + dy*dz; c22 = c22 + dz*dz;
    }
    c[0] = c00/10.0f; c[1] = c01/10.0f; c[2] = c02/10.0f;
    c[3] = c11/10.0f; c[4] = c12/10.0f; c[5] = c22/10.0f;
}

// candidate insert (strict u64 key compare == top_k (d, idx) tie semantics)
#define PROC(p) do { \
    float ddx = qx - (p).x, ddy = qy - (p).y, ddz = qz - (p).z; \
    float dd = fmaf(ddz, ddz, fmaf(ddy, ddy, ddx*ddx)); \
    unsigned long long key = \
        ((unsigned long long)__float_as_uint(dd) << 32) | \
        (unsigned)__float_as_int((p).w); \
    if (key < k9) { \
        unsigned long long ck = key; \
        _Pragma("unroll") \
        for (int s = 0; s < KNN; ++s) { \
            unsigned long long ok2 = keys[s]; \
            bool sw = ok2 > ck; \
            keys[s] = sw ? ck : ok2; \
            ck      = sw ? ok2 : ck; \
        } \
        k9 = keys[KNN-1]; \
        worst = __uint_as_float((unsigned)(k9 >> 32)); \
    } \
} while (0)

// stream a contiguous candidate segment [b, b+n) of S — 2 loads in flight
#define SEGPROC(b, n) do { \
    int _j = (b), _je = (b) + (n); \
    for (; _j + 2 <= _je; _j += 2) { \
        float4 _p0 = cs[_j]; float4 _p1 = cs[_j+1]; \
        PROC(_p0); PROC(_p1); \
    } \
    if (_j < _je) { float4 _p0 = cs[_j]; PROC(_p0); } \
} while (0)

// 4-way compile-time coordinate select (3 cndmasks, once per slot)
#define SEL4(A,B,C,D) (sub == 0 ? (A) : (sub == 1 ? (B) : (sub == 2 ? (C) : (D))))

// ---------------------------------------------------------------------------
// Kernel D (R18 structure): grid 10-NN, FOUR lanes per query, walk
// partitioned by compile-time 4-way checkerboard. R19: cov_compute gated to
// sub==0 (exec-masked: same instruction count, 1/4 the gather loads).
// ---------------------------------------------------------------------------
__global__ __launch_bounds__(256) void knn_main_kernel(
    const float4* __restrict__ P4, const float4* __restrict__ S,
    const int2* __restrict__ combo, float4* __restrict__ Cov,
    int* __restrict__ ovf, unsigned long long* __restrict__ ovf_key,
    int* __restrict__ ovf_count)
{
    int tidg = blockIdx.x * 256 + threadIdx.x;  // 0..262143
    int qid  = tidg >> 2;                       // 0..65535
    int sub  = tidg & 3;
    int pair = qid >> 13;                       // 8 clouds
    int spos = qid & (NN - 1);                  // sorted position
    const float4* __restrict__ cl = P4 + (size_t)pair * NN;
    const float4* __restrict__ cs = S  + (size_t)pair * NN;
    const int2*   __restrict__ cb = combo + (size_t)pair * NCELLS;

    float4 q = cs[spos];
    float qx = q.x, qy = q.y, qz = q.z;
    int qi = __float_as_int(q.w);               // original index in cloud
    int qcx = cellc(qx), qcy = cellc(qy), qcz = cellc(qz);

    unsigned long long keys[KNN];
    #pragma unroll
    for (int s = 0; s < KNN; ++s) keys[s] = 0xFFFFFFFFFFFFFFFFull;
    unsigned long long k9 = keys[KNN-1];
    float worst = __uint_as_float(0xFFFFFFFFu); // NaN: all strict-> tests false

    // ---- phase 1: rho<=1 cube, 9 rows checkerboarded 3/2/2/2 ----
    int x0 = max(qcx - 1, 0), x1 = min(qcx + 1, G - 1);
#define P1SLOT(i, ZA,YA, ZB,YB, ZC,YC, ZD,YD) \
    int rb##i = 0, re##i = 0; \
    { int zz = qcz + SEL4(ZA,ZB,ZC,ZD); \
      int yy = qcy + SEL4(YA,YB,YC,YD); \
      if ((unsigned)zz < G && (unsigned)yy < G) { \
          int cbase = (zz*G + yy)*G; \
          int2 a = cb[cbase + x0]; \
          int2 b = cb[cbase + x1]; \
          rb##i = a.x; re##i = b.x + b.y; } }
    P1SLOT(0, -1,-1, -1,0, -1,1, 0,-1)
    P1SLOT(1,  0, 0,  0,1,  1,-1, 1, 0)
    P1SLOT(2,  1, 1, 99,99, 99,99, 99,99)   // lanes 1-3 invalid -> bounds fail
#undef P1SLOT
#define P1GO(i) SEGPROC(rb##i, re##i - rb##i);
    P1GO(0) P1GO(1) P1GO(2)
#undef P1GO

    // ---- exchange: shared bound = min of 4 lane 10ths (NaN = missing) ----
    float bshared = worst;
    {
        unsigned w1 = (unsigned)__shfl_xor((int)(unsigned)(k9 >> 32), 1, 4);
        bshared = fminf(bshared, __uint_as_float(w1));
        unsigned b32 = __float_as_uint(bshared);
        unsigned w2 = (unsigned)__shfl_xor((int)b32, 2, 4);
        bshared = fminf(bshared, __uint_as_float(w2));
    }

    // ---- phase 2: rho=2 shell (skip iff H^2 > bshared; conservative) ----
    bool skip = (H*H > bshared);                // NaN-safe: NaN -> walk shell
    {
        int xs0 = max(qcx - 2, 0), xs1 = min(qcx + 2, G - 1);
        // 16 outer rows, checkerboarded 4/4/4/4
#define S2SLOT(i, ZA,YA, ZB,YB, ZC,YC, ZD,YD) \
        int sb##i = 0, sn##i = 0; \
        if (!skip) { \
          int zz = qcz + SEL4(ZA,ZB,ZC,ZD); \
          int yy = qcy + SEL4(YA,YB,YC,YD); \
          if ((unsigned)zz < G && (unsigned)yy < G) { \
              float loy = fmaf((float)yy, H, GRID_LO); \
              float loz = fmaf((float)zz, H, GRID_LO); \
              float py = fmaxf(0.0f, fmaxf(loy - qy, qy - (loy + H))); \
              float pz = fmaxf(0.0f, fmaxf(loz - qz, qz - (loz + H))); \
              float pyz = fmaf(pz, pz, py*py); \
              float pw = fminf(worst, bshared); \
              if (!(pyz > pw)) { \
                  int cbase = (zz*G + yy)*G; \
                  int2 a = cb[cbase + xs0]; \
                  int2 b = cb[cbase + xs1]; \
                  sb##i = a.x; sn##i = (b.x + b.y) - a.x; } } }
        S2SLOT(0, -2,-2, -2,-1, -2,0, -2,1)
        S2SLOT(1, -2, 2,  2,-2,  2,-1, 2,0)
        S2SLOT(2,  2, 1,  2, 2, -1,-2, -1,2)
        S2SLOT(3,  0,-2,  0, 2,  1,-2,  1,2)
#undef S2SLOT
        // 18 isolated cells (|dz|<=1,|dy|<=1, dx=+/-2), 5 slots x 4 lanes
#define CSLOT(i, ZA,YA,XA, ZB,YB,XB, ZC,YC,XC, ZD,YD,XD) \
        int tb##i = 0, tn##i = 0; \
        if (!skip) { \
          int zz = qcz + SEL4(ZA,ZB,ZC,ZD); \
          int yy = qcy + SEL4(YA,YB,YC,YD); \
          int xx = qcx + SEL4(XA,XB,XC,XD); \
          if ((unsigned)zz < G && (unsigned)yy < G && (unsigned)xx < G) { \
              float lox = fmaf((float)xx, H, GRID_LO); \
              float loy = fmaf((float)yy, H, GRID_LO); \
              float loz = fmaf((float)zz, H, GRID_LO); \
              float px = fmaxf(0.0f, fmaxf(lox - qx, qx - (lox + H))); \
              float py = fmaxf(0.0f, fmaxf(loy - qy, qy - (loy + H))); \
              float pz = fmaxf(0.0f, fmaxf(loz - qz, qz - (loz + H))); \
              float m2 = fmaf(pz, pz, fmaf(py, py, px*px)); \
              float pw = fminf(worst, bshared); \
              if (!(m2 > pw)) { \
                  int2 a = cb[(zz*G + yy)*G + xx]; \
                  tb##i = a.x; tn##i = a.y; } } }
        CSLOT(0, -1,-1,-2, -1,-1,2, -1,0,-2, -1,0,2)
        CSLOT(1, -1, 1,-2, -1, 1,2,  0,-1,-2, 0,-1,2)
        CSLOT(2,  0, 0,-2,  0, 0,2,  0, 1,-2, 0, 1,2)
        CSLOT(3,  1,-1,-2,  1,-1,2,  1, 0,-2, 1, 0,2)
        CSLOT(4,  1, 1,-2,  1, 1,2, 99,99,0, 99,99,0)
#undef CSLOT
#define S2GO(i) SEGPROC(sb##i, sn##i);
        S2GO(0) S2GO(1) S2GO(2) S2GO(3)
#undef S2GO
#define CGO(i) SEGPROC(tb##i, tn##i);
        CGO(0) CGO(1) CGO(2) CGO(3) CGO(4)
#undef CGO
    }

    // ---- merge the 4 per-lane sorted lists -> exact global top-10 ----
    #pragma unroll
    for (int m = 1; m < 4; m <<= 1) {
        unsigned long long other[KNN];
        #pragma unroll
        for (int s = 0; s < KNN; ++s)
            other[s] = __shfl_xor(keys[s], m, 4);   // snapshot before inserts
        #pragma unroll
        for (int s = 0; s < KNN; ++s) {
            unsigned long long key = other[s];
            if (key < k9) {
                unsigned long long ck = key;
                #pragma unroll
                for (int t = 0; t < KNN; ++t) {
                    unsigned long long ok2 = keys[t];
                    bool sw = ok2 > ck;
                    keys[t] = sw ? ck : ok2;
                    ck      = sw ? ok2 : ck;
                }
                k9 = keys[KNN-1];
            }
        }
    }
    float worst_m = __uint_as_float((unsigned)(k9 >> 32));

    // resolved iff cells beyond the rho<=2 region (gap >= 2H) cannot contribute
    float bf = (float)RCAP * H;
    bool resolved = (bf*bf > worst_m);          // strict; NaN (unfilled) -> false
    if (resolved && sub == 0) {
        float c[6];
        cov_compute(cl, keys, c);               // sub==0 only: 1/4 gather loads
        size_t o = ((size_t)pair*NN + qi)*2;
        Cov[o]   = make_float4(c[0], c[1], c[2], c[3]);
        Cov[o+1] = make_float4(c[4], c[5], 0.0f, 0.0f);
    } else if (!resolved && sub == 0) {
        int pos = atomicAdd(ovf_count, 1);
        ovf[pos] = (pair << 13) | qi;
        ovf_key[pos] = k9;      // merged 10th-best: valid upper bound on true
    }                           // 10th key (subset 10th >= full-set 10th)
}

// ---------------------------------------------------------------------------
// Kernel D2: brute-force overflow (R14 config), one query per block. Bound
// gate skips the insert chain for provably-excluded candidates. Writes
// covariance (eigh relocated to eigh_loss).
// ---------------------------------------------------------------------------
#define BRUTE_BLOCKS 4096
__global__ __launch_bounds__(256) void brute_kernel(
    const float4* __restrict__ P4, const int* __restrict__ ovf,
    const unsigned long long* __restrict__ ovf_key,
    const int* __restrict__ ovf_count, float4* __restrict__ Cov)
{
    __shared__ unsigned long long wl[4][KNN];
    int tid = threadIdx.x;
    int lane = tid & 63;
    int wid = tid >> 6;
    int count = *ovf_count;

    for (int oi = blockIdx.x; oi < count; oi += BRUTE_BLOCKS) {
        int rec = ovf[oi];
        unsigned long long bound = ovf_key[oi];
        float bound_d = __uint_as_float((unsigned)(bound >> 32)); // NaN if unfilled
        int pair = rec >> 13;
        int qi = rec & (NN - 1);
        const float4* __restrict__ cl = P4 + (size_t)pair * NN;
        float4 q = cl[qi];
        float qx = q.x, qy = q.y, qz = q.z;

        unsigned long long keys[KNN];
        #pragma unroll
        for (int s = 0; s < KNN; ++s) keys[s] = 0xFFFFFFFFFFFFFFFFull;
        unsigned long long k9 = keys[KNN-1];

        // per-lane scan with bound gate; ties at dd==bound_d pass (exact)
#define BPROC(p, jj) do { \
        float ddx = qx - (p).x, ddy = qy - (p).y, ddz = qz - (p).z; \
        float dd = fmaf(ddz, ddz, fmaf(ddy, ddy, ddx*ddx)); \
        if (!(dd > bound_d)) { \
            unsigned long long key = \
                ((unsigned long long)__float_as_uint(dd) << 32) | (unsigned)(jj); \
            if (key < k9) { \
                unsigned long long ck = key; \
                _Pragma("unroll") \
                for (int s = 0; s < KNN; ++s) { \
                    unsigned long long ok2 = keys[s]; \
                    bool sw = ok2 > ck; \
                    keys[s] = sw ? ck : ok2; \
                    ck      = sw ? ok2 : ck; \
                } \
                k9 = keys[KNN-1]; \
            } \
        } \
    } while (0)
        #pragma unroll 1
        for (int j = tid; j < NN; j += 1024) {  // 8 iterations, 4 loads each
            float4 p0 = cl[j];
            float4 p1 = cl[j + 256];
            float4 p2 = cl[j + 512];
            float4 p3 = cl[j + 768];
            BPROC(p0, j);
            BPROC(p1, j + 256);
            BPROC(p2, j + 512);
            BPROC(p3, j + 768);
        }
#undef BPROC

        // in-wave tree merge -> every lane holds its wave's top-10
        #pragma unroll
        for (int m = 1; m < 64; m <<= 1) {
            unsigned long long other[KNN];
            #pragma unroll
            for (int s = 0; s < KNN; ++s)
                other[s] = __shfl_xor(keys[s], m);  // snapshot before inserts
            #pragma unroll
            for (int s = 0; s < KNN; ++s) {
                unsigned long long key = other[s];
                if (key < k9) {
                    unsigned long long ck = key;
                    #pragma unroll
                    for (int t = 0; t < KNN; ++t) {
                        unsigned long long ok2 = keys[t];
                        bool sw = ok2 > ck;
                        keys[t] = sw ? ck : ok2;
                        ck      = sw ? ok2 : ck;
                    }
                    k9 = keys[KNN-1];
                }
            }
        }

        // cross-wave merge via LDS (4 sorted lists)
        if (lane == 0) {
            #pragma unroll
            for (int s = 0; s < KNN; ++s) wl[wid][s] = keys[s];
        }
        __syncthreads();
        if (wid == 0) {
            for (int w2 = 1; w2 < 4; ++w2) {
                #pragma unroll
                for (int s = 0; s < KNN; ++s) {
                    unsigned long long key = wl[w2][s];
                    if (key >= k9) break;       // lists sorted ascending
                    unsigned long long ck = key;
                    #pragma unroll
                    for (int t = 0; t < KNN; ++t) {
                        unsigned long long ok2 = keys[t];
                        bool sw = ok2 > ck;
                        keys[t] = sw ? ck : ok2;
                        ck      = sw ? ok2 : ck;
                    }
                    k9 = keys[KNN-1];
                }
            }
            if (lane == 0) {
                float c[6];
                cov_compute(cl, keys, c);
                size_t o = ((size_t)pair*NN + qi)*2;
                Cov[o]   = make_float4(c[0], c[1], c[2], c[3]);
                Cov[o+1] = make_float4(c[4], c[5], 0.0f, 0.0f);
            }
        }
        __syncthreads();                        // protect wl for next query
    }
}

// ---------------------------------------------------------------------------
// Kernel E (R19): fused eigh + loss, ONE eigh per thread over 2*BN threads
// (512 blocks = 1024 waves, 2x the R18 parallelism for the divergent eigh).
// Thread 2k handles gt[k], thread 2k+1 handles pred[k]; normals exchanged
// in-wave via shfl_xor(1); even lanes compute 1-cos; block reduce; atomic.
// Identical eigh inputs -> bit-identical normals (summation grouping only).
// ---------------------------------------------------------------------------
__global__ __launch_bounds__(256) void eigh_loss_kernel(
    const float4* __restrict__ Cov, float* __restrict__ accum,
    unsigned* __restrict__ counter, float* __restrict__ out)
{
    int tid = threadIdx.x;
    int t = blockIdx.x * 256 + tid;            // 0..2*BN-1
    int k = t >> 1;                            // pair index 0..BN-1
    int cld = t & 1;                           // 0 = gt, 1 = pred
    size_t ci = ((size_t)(cld ? BN + k : k)) * 2;
    float4 a0 = Cov[ci], a1 = Cov[ci + 1];
    float n[3];
    eigh3_smallest(a0.x, a0.y, a0.z, a0.w, a1.x, a1.y, n);

    // exchange with partner lane (2k <-> 2k+1 always share a wave)
    float ox = __shfl_xor(n[0], 1);
    float oy = __shfl_xor(n[1], 1);
    float oz = __shfl_xor(n[2], 1);

    float v = 0.0f;
    if (cld == 0) {
        float gx=n[0], gy=n[1], gz=n[2];
        float hx=ox,  hy=oy,  hz=oz;
        float dot = fmaf(gx,hx,fmaf(gy,hy,gz*hz));
        float ng  = sqrtf(fmaf(gx,gx,fmaf(gy,gy,gz*gz)));
        float nh  = sqrtf(fmaf(hx,hx,fmaf(hy,hy,hz*hz)));
        float den = fmaxf(ng*nh, 1e-8f);
        v = 1.0f - dot/den;
    }

    __shared__ float red[256];
    red[tid] = v;                              // odd lanes contribute 0
    __syncthreads();
    for (int s = 128; s > 0; s >>= 1) {
        if (tid < s) red[tid] += red[tid+s];
        __syncthreads();
    }
    if (tid == 0) {
        atomicAdd(accum, red[0]);
        __threadfence();
        unsigned old = atomicAdd(counter, 1u);
        if (old == (unsigned)(2*BN/256 - 1)) {
            float tot = atomicAdd(accum, 0.0f);
            out[0] = tot * (1.0f/(float)BN);
        }
    }
}

// ---------------------------------------------------------------------------
extern "C" void kernel_launch(void* const* d_in, const int* in_sizes, int n_in,
                              void* d_out, int out_size, void* d_ws, size_t ws_size,
                              hipStream_t stream)
{
    (void)in_sizes; (void)n_in; (void)out_size; (void)ws_size;
    const float*    gt   = (const float*)d_in[0];
    const float*    pred = (const float*)d_in[1];
    const unsigned* idxw = (const unsigned*)d_in[2];
    float* out = (float*)d_out;

    char* w = (char*)d_ws;
    float4* P4   = (float4*)w;                         w += (size_t)2*BN*16;   // 1 MB
    float4* S    = (float4*)w;                         w += (size_t)2*BN*16;   // 1 MB
    int*    hist = (int*)w;                            w += (size_t)8*NCELLS*4;   // 1 MB
    int2*   combo = (int2*)w;                          w += (size_t)8*NCELLS*8;   // 2 MB
    float4* Cov  = (float4*)w;                         w += (size_t)2*BN*32;   // 2 MB
    float*  accum = (float*)w;                         w += 16;
    unsigned* counter = (unsigned*)(accum + 1);
    int*    ovf_count = (int*)(accum + 2);
    int*    ovf  = (int*)w;                            w += (size_t)2*BN*4;    // 0.25 MB
    unsigned long long* ovf_key = (unsigned long long*)w;  w += (size_t)2*BN*8; // 0.5 MB

    hipMemsetAsync(hist, 0, (size_t)8*NCELLS*4, stream);
    hipLaunchKernelGGL(prep_kernel,    dim3(2*BN/256), dim3(256),  0, stream,
                       gt, pred, idxw, P4, hist, accum, counter, ovf_count);
    hipLaunchKernelGGL(scan_kernel,    dim3(8),        dim3(1024), 0, stream,
                       hist, combo);
    hipLaunchKernelGGL(scatter_kernel, dim3(2*BN/256), dim3(256),  0, stream,
                       P4, hist, combo, S);
    hipLaunchKernelGGL(knn_main_kernel, dim3(2*BN*4/256), dim3(256), 0, stream,
                       P4, S, combo, Cov, ovf, ovf_key, ovf_count);
    hipLaunchKernelGGL(brute_kernel,   dim3(BRUTE_BLOCKS), dim3(256), 0, stream,
                       P4, ovf, ovf_key, ovf_count, Cov);
    hipLaunchKernelGGL(eigh_loss_kernel, dim3(2*BN/256), dim3(256), 0, stream,
                       Cov, accum, counter, out);
}